// Round 4
// baseline (3475.491 us; speedup 1.0000x reference)
//
#include <hip/hip_runtime.h>

typedef unsigned short u16;
typedef unsigned int   u32;

typedef __bf16 bf16x8 __attribute__((ext_vector_type(8)));
typedef float  f32x4  __attribute__((ext_vector_type(4)));

typedef __attribute__((address_space(1))) const u32* gas_u32;
typedef __attribute__((address_space(3))) u32*       las_u32;

#define B_  4
#define S_  1024
#define D_  4096
#define H_  32
#define HD_ 128
#define M_  4096

__device__ __forceinline__ void gload16(const void* g, void* l) {
  __builtin_amdgcn_global_load_lds((gas_u32)g, (las_u32)l, 16, 0, 0);
}

__device__ __forceinline__ u16 f2b(float x) {
  u32 u = __float_as_uint(x);
  u32 r = (u + 0x7fffu + ((u >> 16) & 1u)) >> 16;
  return (u16)r;
}
__device__ __forceinline__ float b2f(u16 x) {
  return __uint_as_float((u32)x << 16);
}

// ---------------- fp32 -> bf16 convert: 4 tensors in one dispatch ----------------
__global__ __launch_bounds__(256) void k_cvt4(const float* __restrict__ sa,
                                              const float* __restrict__ sb,
                                              const float* __restrict__ sc,
                                              const float* __restrict__ sd,
                                              u16* __restrict__ da,
                                              u16* __restrict__ db,
                                              u16* __restrict__ dc,
                                              u16* __restrict__ dd) {
  const int sel = blockIdx.x >> 13;          // 4 x 8192 blocks
  const float* src = sel == 0 ? sa : sel == 1 ? sb : sel == 2 ? sc : sd;
  u16*         dst = sel == 0 ? da : sel == 1 ? db : sel == 2 ? dc : dd;
  size_t i = (size_t)(blockIdx.x & 8191) * 256 + threadIdx.x;
  const float4* s = (const float4*)src + i * 2;
  float4 a = s[0], b = s[1];
  uint4 o;
  o.x = (u32)f2b(a.x) | ((u32)f2b(a.y) << 16);
  o.y = (u32)f2b(a.z) | ((u32)f2b(a.w) << 16);
  o.z = (u32)f2b(b.x) | ((u32)f2b(b.y) << 16);
  o.w = (u32)f2b(b.z) | ((u32)f2b(b.w) << 16);
  ((uint4*)dst)[i] = o;
}

// ---------------- LoRA intermediates: t_q = x@wq_a^T, t_v = x@wv_a^T (fp32 exact) ----
__global__ __launch_bounds__(256) void k_lora_t(const float* __restrict__ x,
                                                const float* __restrict__ wqa,
                                                const float* __restrict__ wva,
                                                float* __restrict__ tq,
                                                float* __restrict__ tv) {
  __shared__ float xs[32][136];
  __shared__ float was[32][136];
  const int tid = threadIdx.x;
  const int m0 = blockIdx.x * 32;
  const int mr = tid >> 3, rg = tid & 7;
  float a0 = 0.f, a1 = 0.f, a2 = 0.f, a3 = 0.f;
  for (int kc = 0; kc < 4096; kc += 128) {
    #pragma unroll
    for (int i = 0; i < 4; i++) {
      int e = (tid + 256 * i) * 4;
      int row = e >> 7, col = e & 127;
      *(float4*)&xs[row][col] = *(const float4*)&x[(size_t)(m0 + row) * 4096 + kc + col];
      const float* wsrc = (row < 16) ? &wqa[row * 4096 + kc + col]
                                     : &wva[(row - 16) * 4096 + kc + col];
      *(float4*)&was[row][col] = *(const float4*)wsrc;
    }
    __syncthreads();
    #pragma unroll 8
    for (int ks = 0; ks < 32; ks++) {
      float4 xv = *(float4*)&xs[mr][ks * 4];
      float4 w0 = *(float4*)&was[rg][ks * 4];
      float4 w1 = *(float4*)&was[rg + 8][ks * 4];
      float4 w2 = *(float4*)&was[rg + 16][ks * 4];
      float4 w3 = *(float4*)&was[rg + 24][ks * 4];
      a0 += xv.x * w0.x + xv.y * w0.y + xv.z * w0.z + xv.w * w0.w;
      a1 += xv.x * w1.x + xv.y * w1.y + xv.z * w1.z + xv.w * w1.w;
      a2 += xv.x * w2.x + xv.y * w2.y + xv.z * w2.z + xv.w * w2.w;
      a3 += xv.x * w3.x + xv.y * w3.y + xv.z * w3.z + xv.w * w3.w;
    }
    __syncthreads();
  }
  tq[(m0 + mr) * 16 + rg]     = a0;
  tq[(m0 + mr) * 16 + rg + 8] = a1;
  tv[(m0 + mr) * 16 + rg]     = a2;
  tv[(m0 + mr) * 16 + rg + 8] = a3;
}

// ---------------- main GEMM: C(4096x4096) = A(bf16) @ B(bf16)^T [+ 2*T@WB^T] --------
// m97 structure: 128x128 tile, BK=32, 4 waves (2x2 of 64x64), global_load_lds w16,
// XCD-aware swizzle (1024 blocks % 8 == 0 -> bijective).
template<bool LORA, bool F32OUT>
__global__ __launch_bounds__(256) void k_gemm(const u16* __restrict__ A,
                                              const u16* __restrict__ Bw,
                                              float* __restrict__ Cf,
                                              u16* __restrict__ Cb,
                                              const float* __restrict__ T,
                                              const float* __restrict__ WB) {
  constexpr int K = 4096, N = 4096;
  __shared__ union {
    u16   ab[2][128 * 32];   // [0]=A tile, [1]=B tile (8 KB each)
    float lr[2][128 * 16];   // epilogue: [0]=T rows, [1]=WB rows (8 KB each)
  } sm;
  const int tid = threadIdx.x;
  const int w = tid >> 6, l = tid & 63;
  const int wr = w >> 1, wc = w & 1;
  const int fr = l & 15, fq = l >> 4;
  const int bid = blockIdx.x;
  const int swz = (bid & 7) * 128 + (bid >> 3);       // XCD swizzle
  const int m0 = (swz >> 5) << 7;
  const int n0 = (swz & 31) << 7;
  const int c0 = tid, c1 = tid + 256;
  const u16* Ab0 = A + (size_t)(m0 + (c0 >> 2)) * K + (c0 & 3) * 8;
  const u16* Ab1 = A + (size_t)(m0 + (c1 >> 2)) * K + (c1 & 3) * 8;
  const u16* Bb0 = Bw + (size_t)(n0 + (c0 >> 2)) * K + (c0 & 3) * 8;
  const u16* Bb1 = Bw + (size_t)(n0 + (c1 >> 2)) * K + (c1 & 3) * 8;
  u16* la0 = &sm.ab[0][c0 * 8];
  u16* la1 = &sm.ab[0][c1 * 8];
  u16* lb0 = &sm.ab[1][c0 * 8];
  u16* lb1 = &sm.ab[1][c1 * 8];
  f32x4 acc[4][4];
  #pragma unroll
  for (int i = 0; i < 4; i++)
    #pragma unroll
    for (int j = 0; j < 4; j++) acc[i][j] = (f32x4){0.f, 0.f, 0.f, 0.f};
  const int ar = wr * 64 + fr, br = wc * 64 + fr, kc = fq * 8;
  for (int kt = 0; kt < K; kt += 32) {
    gload16(Ab0 + kt, la0);
    gload16(Ab1 + kt, la1);
    gload16(Bb0 + kt, lb0);
    gload16(Bb1 + kt, lb1);
    __syncthreads();
    bf16x8 af[4], bv[4];
    #pragma unroll
    for (int i = 0; i < 4; i++) af[i] = *(const bf16x8*)&sm.ab[0][(ar + i * 16) * 32 + kc];
    #pragma unroll
    for (int j = 0; j < 4; j++) bv[j] = *(const bf16x8*)&sm.ab[1][(br + j * 16) * 32 + kc];
    #pragma unroll
    for (int i = 0; i < 4; i++)
      #pragma unroll
      for (int j = 0; j < 4; j++)
        acc[i][j] = __builtin_amdgcn_mfma_f32_16x16x32_bf16(af[i], bv[j], acc[i][j], 0, 0, 0);
    __syncthreads();
  }
  if (LORA) {
    #pragma unroll
    for (int i = 0; i < 2; i++) {
      int e = (tid + 256 * i) * 4;
      int r = e >> 4, cc = e & 15;
      *(float4*)&sm.lr[0][r * 16 + cc] = *(const float4*)&T[(m0 + r) * 16 + cc];
      *(float4*)&sm.lr[1][r * 16 + cc] = *(const float4*)&WB[(n0 + r) * 16 + cc];
    }
    __syncthreads();
  }
  #pragma unroll
  for (int i = 0; i < 4; i++) {
    #pragma unroll
    for (int j = 0; j < 4; j++) {
      const int row = wr * 64 + i * 16 + fq * 4;
      const int col = wc * 64 + j * 16 + fr;
      #pragma unroll
      for (int jj = 0; jj < 4; jj++) {
        float v = acc[i][j][jj];
        if (LORA) {
          const float* trp = &sm.lr[0][(row + jj) * 16];
          const float* wbp = &sm.lr[1][col * 16];
          float d = 0.f;
          #pragma unroll
          for (int r = 0; r < 16; r++) d += trp[r] * wbp[r];
          v += 2.0f * d;
        }
        if (F32OUT) Cf[(size_t)(m0 + row + jj) * N + (n0 + col)] = v;
        else        Cb[(size_t)(m0 + row + jj) * N + (n0 + col)] = f2b(v);
      }
    }
  }
}

// ---------------- RoPE both tensors: (b,s,h,d)bf16 -> (b,h,s,d)bf16 ------------------
// blocks [0,16384) = Q (scale 1/sqrt(HD)), [16384,32768) = K (scale 1)
__global__ __launch_bounds__(256) void k_rope2(const u16* __restrict__ qin,
                                               const u16* __restrict__ kin,
                                               u16* __restrict__ qout,
                                               u16* __restrict__ kout,
                                               const float* __restrict__ fc,
                                               const float* __restrict__ fs) {
  const int sel = blockIdx.x >> 14;
  const u16* in  = sel ? kin  : qin;
  u16*       out = sel ? kout : qout;
  const float scale = sel ? 1.0f : 0.08838834764831845f;
  const int tid = (blockIdx.x & 16383) * 256 + threadIdx.x;   // B*H*S*32 threads
  const int c4 = tid & 31;
  const int s  = (tid >> 5) & 1023;
  const int h  = (tid >> 15) & 31;
  const int b  = tid >> 20;
  const ushort4 v = *(const ushort4*)&in[(((size_t)(b * 1024 + s) * 32 + h) * 128) + c4 * 4];
  const float2 c = *(const float2*)&fc[s * 64 + c4 * 2];
  const float2 sn = *(const float2*)&fs[s * 64 + c4 * 2];
  float vx = b2f(v.x), vy = b2f(v.y), vz = b2f(v.z), vw = b2f(v.w);
  float o0 = (vx * c.x - vy * sn.x) * scale;
  float o1 = (vx * sn.x + vy * c.x) * scale;
  float o2 = (vz * c.y - vw * sn.y) * scale;
  float o3 = (vz * sn.y + vw * c.y) * scale;
  uint2 o;
  o.x = (u32)f2b(o0) | ((u32)f2b(o1) << 16);
  o.y = (u32)f2b(o2) | ((u32)f2b(o3) << 16);
  *(uint2*)&out[(((size_t)(b * 32 + h) * 1024 + s) * 128) + c4 * 4] = o;
}

// ---- fused: V transpose (b,s,h,d)->(b,h,d,s) [blocks 0..16383]  +  wo fp32->bf16
//      convert [blocks 16384..24575] ----
__global__ __launch_bounds__(256) void k_vt_cvt(const u16* __restrict__ Vb,
                                                u16* __restrict__ vt,
                                                const float* __restrict__ wo,
                                                u16* __restrict__ wo_bf) {
  __shared__ u16 tile[32][36];
  const int bid = blockIdx.x;
  const int t = threadIdx.x;
  if (bid < 16384) {                     // V transpose: B*H*(S/32)*(HD/32) tiles
    const int dt = bid & 3;
    const int st = (bid >> 2) & 31;
    const int bh = bid >> 7;
    const int r = t >> 3, c4 = (t & 7) * 4;
    const ushort4 v = *(const ushort4*)
        &Vb[((size_t)((bh >> 5) * 1024 + st * 32 + r) * 32 + (bh & 31)) * 128 + dt * 32 + c4];
    tile[r][c4] = v.x; tile[r][c4 + 1] = v.y; tile[r][c4 + 2] = v.z; tile[r][c4 + 3] = v.w;
    __syncthreads();
    uint2 o;
    o.x = (u32)tile[c4][r]     | ((u32)tile[c4 + 1][r] << 16);
    o.y = (u32)tile[c4 + 2][r] | ((u32)tile[c4 + 3][r] << 16);
    *(uint2*)&vt[((size_t)bh * 128 + dt * 32 + r) * 1024 + st * 32 + c4] = o;
  } else {                               // wo convert: 8192 blocks x 256 thr x 8 elems
    size_t i = (size_t)(bid - 16384) * 256 + t;
    const float4* s = (const float4*)wo + i * 2;
    float4 a = s[0], b = s[1];
    uint4 o;
    o.x = (u32)f2b(a.x) | ((u32)f2b(a.y) << 16);
    o.y = (u32)f2b(a.z) | ((u32)f2b(a.w) << 16);
    o.z = (u32)f2b(b.x) | ((u32)f2b(b.y) << 16);
    o.w = (u32)f2b(b.z) | ((u32)f2b(b.w) << 16);
    ((uint4*)wo_bf)[i] = o;
  }
}

// ---------------- flash attention: 1 wave = 16 q-rows, causal, online softmax -------
__global__ __launch_bounds__(64) void k_attn(const u16* __restrict__ qb,
                                             const u16* __restrict__ kb,
                                             const u16* __restrict__ vt,
                                             u16* __restrict__ ob) {
  __shared__ u16 P[16 * 32];
  const int bid = blockIdx.x;            // B*H*(S/16) = 8192
  const int qt = bid & 63;
  const int bh = bid >> 6;
  const int q0 = qt * 16;
  const int l = threadIdx.x;
  const int c = l & 15, g = l >> 4;
  const u16* qbase = qb + (size_t)bh * (S_ * HD_);
  const u16* kbase = kb + (size_t)bh * (S_ * HD_);
  const u16* vbase = vt + (size_t)bh * (HD_ * S_);
  bf16x8 qf[4];
  #pragma unroll
  for (int ks = 0; ks < 4; ks++)
    qf[ks] = *(const bf16x8*)&qbase[(q0 + c) * 128 + ks * 32 + g * 8];
  f32x4 accO[8];
  #pragma unroll
  for (int d = 0; d < 8; d++) accO[d] = (f32x4){0.f, 0.f, 0.f, 0.f};
  float mrun[4] = {-1e30f, -1e30f, -1e30f, -1e30f};
  float lrun[4] = {0.f, 0.f, 0.f, 0.f};
  const int nkb = (q0 + 47) >> 5;
  for (int kbi = 0; kbi < nkb; kbi++) {
    const int k0 = kbi * 32;
    f32x4 s0 = (f32x4){0.f, 0.f, 0.f, 0.f}, s1 = (f32x4){0.f, 0.f, 0.f, 0.f};
    #pragma unroll
    for (int ks = 0; ks < 4; ks++) {
      bf16x8 b0 = *(const bf16x8*)&kbase[(k0 + c) * 128 + ks * 32 + g * 8];
      bf16x8 b1 = *(const bf16x8*)&kbase[(k0 + 16 + c) * 128 + ks * 32 + g * 8];
      s0 = __builtin_amdgcn_mfma_f32_16x16x32_bf16(qf[ks], b0, s0, 0, 0, 0);
      s1 = __builtin_amdgcn_mfma_f32_16x16x32_bf16(qf[ks], b1, s1, 0, 0, 0);
    }
    if (kbi == nkb - 1) {           // only the last block can be causally partial
      #pragma unroll
      for (int j = 0; j < 4; j++) {
        int q = q0 + g * 4 + j;
        if (k0 + c > q)      s0[j] = -1e9f;
        if (k0 + 16 + c > q) s1[j] = -1e9f;
      }
    }
    float pv0[4], pv1[4], corr[4];
    #pragma unroll
    for (int j = 0; j < 4; j++) {
      float mx = fmaxf(s0[j], s1[j]);
      #pragma unroll
      for (int off = 8; off; off >>= 1) mx = fmaxf(mx, __shfl_xor(mx, off, 16));
      float mn = fmaxf(mrun[j], mx);
      corr[j] = __expf(mrun[j] - mn);
      mrun[j] = mn;
      float p0 = __expf(s0[j] - mn);
      float p1 = __expf(s1[j] - mn);
      float rs = p0 + p1;
      #pragma unroll
      for (int off = 8; off; off >>= 1) rs += __shfl_xor(rs, off, 16);
      lrun[j] = lrun[j] * corr[j] + rs;
      pv0[j] = p0; pv1[j] = p1;
    }
    __syncthreads();                 // prior iteration's P reads drained
    #pragma unroll
    for (int j = 0; j < 4; j++) {
      P[(g * 4 + j) * 32 + c]      = f2b(pv0[j]);
      P[(g * 4 + j) * 32 + 16 + c] = f2b(pv1[j]);
    }
    __syncthreads();                 // P visible across lanes
    bf16x8 pa = *(const bf16x8*)&P[c * 32 + g * 8];
    #pragma unroll
    for (int d = 0; d < 8; d++) {
      #pragma unroll
      for (int j = 0; j < 4; j++) accO[d][j] *= corr[j];
    }
    #pragma unroll
    for (int d = 0; d < 8; d++) {
      bf16x8 vf = *(const bf16x8*)&vbase[(d * 16 + c) * 1024 + k0 + g * 8];
      accO[d] = __builtin_amdgcn_mfma_f32_16x16x32_bf16(pa, vf, accO[d], 0, 0, 0);
    }
  }
  float inv[4];
  #pragma unroll
  for (int j = 0; j < 4; j++) inv[j] = 1.0f / lrun[j];
  #pragma unroll
  for (int d = 0; d < 8; d++) {
    #pragma unroll
    for (int j = 0; j < 4; j++) {
      float val = accO[d][j] * inv[j];
      ob[(size_t)((bh >> 5) * 1024 + q0 + g * 4 + j) * 4096 + (bh & 31) * 128 + d * 16 + c]
          = f2b(val);
    }
  }
}

// =====================================================================================
extern "C" void kernel_launch(void* const* d_in, const int* in_sizes, int n_in,
                              void* d_out, int out_size, void* d_ws, size_t ws_size,
                              hipStream_t stream) {
  const float* x    = (const float*)d_in[0];
  const float* wq_w = (const float*)d_in[1];
  const float* wq_a = (const float*)d_in[2];
  const float* wq_b = (const float*)d_in[3];
  const float* wk_w = (const float*)d_in[4];
  const float* wv_w = (const float*)d_in[5];
  const float* wv_a = (const float*)d_in[6];
  const float* wv_b = (const float*)d_in[7];
  const float* wo_w = (const float*)d_in[8];
  const float* fc   = (const float*)d_in[9];
  const float* fs   = (const float*)d_in[10];
  // d_in[11] = mask (causal, applied analytically), d_in[12] = start_pos (0)

  // 7 x 32MB slots, time-aliased along the serial stream order (+ 2 small fp32 bufs)
  char* p = (char*)d_ws;
  const size_t SZ_BF = (size_t)M_ * D_ * 2;   // 32 MB
  u16* s0 = (u16*)(p + 0 * SZ_BF);   // x_bf   -> wo_bf
  u16* s1 = (u16*)(p + 1 * SZ_BF);   // wq_bf  -> att_bf
  u16* s2 = (u16*)(p + 2 * SZ_BF);   // wk_bf  -> q_bf
  u16* s3 = (u16*)(p + 3 * SZ_BF);   // wv_bf  -> k_bf
  u16* s4 = (u16*)(p + 4 * SZ_BF);   // Qb     -> v_t
  u16* s5 = (u16*)(p + 5 * SZ_BF);   // Kb
  u16* s6 = (u16*)(p + 6 * SZ_BF);   // Vb
  float* t_q = (float*)(p + 7 * SZ_BF);
  float* t_v = t_q + (size_t)M_ * 16;

  // 1. bf16 conversions (x, wq, wk, wv) in one dispatch
  k_cvt4<<<32768, 256, 0, stream>>>(x, wq_w, wk_w, wv_w, s0, s1, s2, s3);

  // 2. LoRA intermediates (fp32 exact, from fp32 x)
  k_lora_t<<<128, 256, 0, stream>>>(x, wq_a, wv_a, t_q, t_v);

  // 3. projections (bf16 MFMA, bf16 out; LoRA rank-16 fp32 epilogue for Q and V)
  k_gemm<true,  false><<<1024, 256, 0, stream>>>(s0, s1, nullptr, s4, t_q, wq_b);        // Qb
  k_gemm<false, false><<<1024, 256, 0, stream>>>(s0, s2, nullptr, s5, nullptr, nullptr); // Kb
  k_gemm<true,  false><<<1024, 256, 0, stream>>>(s0, s3, nullptr, s6, t_v, wv_b);        // Vb

  // 4. RoPE Q (+1/sqrt(HD)) and K -> (b,h,s,d) bf16, one dispatch
  k_rope2<<<32768, 256, 0, stream>>>(s4, s5, s2, s3, fc, fs);  // Qb->q_bf(s2), Kb->k_bf(s3)

  // 5. V -> (b,h,d,s) bf16 (into s4; Qb dead)  +  wo convert (into s0; x_bf dead)
  k_vt_cvt<<<24576, 256, 0, stream>>>(s6, s4, wo_w, s0);

  // 6. causal flash attention -> (b,s,h*d) bf16 (wq_bf slot s1 dead)
  k_attn<<<8192, 64, 0, stream>>>(s2, s3, s4, s1);

  // 7. output projection -> fp32 d_out
  k_gemm<false, true><<<1024, 256, 0, stream>>>(s1, s0, (float*)d_out, nullptr, nullptr, nullptr);
}

// Round 5
// 2496.254 us; speedup vs baseline: 1.3923x; 1.3923x over previous
//
#include <hip/hip_runtime.h>

typedef unsigned short u16;
typedef unsigned int   u32;

typedef __bf16 bf16x8 __attribute__((ext_vector_type(8)));
typedef float  f32x4  __attribute__((ext_vector_type(4)));

typedef __attribute__((address_space(1))) const u32* gas_u32;
typedef __attribute__((address_space(3))) u32*       las_u32;

#define B_  4
#define S_  1024
#define D_  4096
#define H_  32
#define HD_ 128
#define M_  4096

__device__ __forceinline__ void gload16(const void* g, void* l) {
  __builtin_amdgcn_global_load_lds((gas_u32)g, (las_u32)l, 16, 0, 0);
}

__device__ __forceinline__ u16 f2b(float x) {
  u32 u = __float_as_uint(x);
  u32 r = (u + 0x7fffu + ((u >> 16) & 1u)) >> 16;
  return (u16)r;
}
__device__ __forceinline__ float b2f(u16 x) {
  return __uint_as_float((u32)x << 16);
}

// ---------------- fp32 -> bf16 convert: 4 tensors in one dispatch ----------------
__global__ __launch_bounds__(256) void k_cvt4(const float* __restrict__ sa,
                                              const float* __restrict__ sb,
                                              const float* __restrict__ sc,
                                              const float* __restrict__ sd,
                                              u16* __restrict__ da,
                                              u16* __restrict__ db,
                                              u16* __restrict__ dc,
                                              u16* __restrict__ dd) {
  const int sel = blockIdx.x >> 13;          // 4 x 8192 blocks
  const float* src = sel == 0 ? sa : sel == 1 ? sb : sel == 2 ? sc : sd;
  u16*         dst = sel == 0 ? da : sel == 1 ? db : sel == 2 ? dc : dd;
  size_t i = (size_t)(blockIdx.x & 8191) * 256 + threadIdx.x;
  const float4* s = (const float4*)src + i * 2;
  float4 a = s[0], b = s[1];
  uint4 o;
  o.x = (u32)f2b(a.x) | ((u32)f2b(a.y) << 16);
  o.y = (u32)f2b(a.z) | ((u32)f2b(a.w) << 16);
  o.z = (u32)f2b(b.x) | ((u32)f2b(b.y) << 16);
  o.w = (u32)f2b(b.z) | ((u32)f2b(b.w) << 16);
  ((uint4*)dst)[i] = o;
}

// ---------------- LoRA intermediates: t_q = x@wq_a^T, t_v = x@wv_a^T (fp32 exact) ----
__global__ __launch_bounds__(256) void k_lora_t(const float* __restrict__ x,
                                                const float* __restrict__ wqa,
                                                const float* __restrict__ wva,
                                                float* __restrict__ tq,
                                                float* __restrict__ tv) {
  __shared__ float xs[32][136];
  __shared__ float was[32][136];
  const int tid = threadIdx.x;
  const int m0 = blockIdx.x * 32;
  const int mr = tid >> 3, rg = tid & 7;
  float a0 = 0.f, a1 = 0.f, a2 = 0.f, a3 = 0.f;
  for (int kc = 0; kc < 4096; kc += 128) {
    #pragma unroll
    for (int i = 0; i < 4; i++) {
      int e = (tid + 256 * i) * 4;
      int row = e >> 7, col = e & 127;
      *(float4*)&xs[row][col] = *(const float4*)&x[(size_t)(m0 + row) * 4096 + kc + col];
      const float* wsrc = (row < 16) ? &wqa[row * 4096 + kc + col]
                                     : &wva[(row - 16) * 4096 + kc + col];
      *(float4*)&was[row][col] = *(const float4*)wsrc;
    }
    __syncthreads();
    #pragma unroll 8
    for (int ks = 0; ks < 32; ks++) {
      float4 xv = *(float4*)&xs[mr][ks * 4];
      float4 w0 = *(float4*)&was[rg][ks * 4];
      float4 w1 = *(float4*)&was[rg + 8][ks * 4];
      float4 w2 = *(float4*)&was[rg + 16][ks * 4];
      float4 w3 = *(float4*)&was[rg + 24][ks * 4];
      a0 += xv.x * w0.x + xv.y * w0.y + xv.z * w0.z + xv.w * w0.w;
      a1 += xv.x * w1.x + xv.y * w1.y + xv.z * w1.z + xv.w * w1.w;
      a2 += xv.x * w2.x + xv.y * w2.y + xv.z * w2.z + xv.w * w2.w;
      a3 += xv.x * w3.x + xv.y * w3.y + xv.z * w3.z + xv.w * w3.w;
    }
    __syncthreads();
  }
  tq[(m0 + mr) * 16 + rg]     = a0;
  tq[(m0 + mr) * 16 + rg + 8] = a1;
  tv[(m0 + mr) * 16 + rg]     = a2;
  tv[(m0 + mr) * 16 + rg + 8] = a3;
}

// ---------------- main GEMM: C(4096x4096) = A(bf16) @ B(bf16)^T [+ 2*T@WB^T] --------
// 128x128 tile, BK=32, 4 waves (2x2 of 64x64), global_load_lds w16, XCD swizzle.
// LDS bank-conflict fix: both-sides chunk swizzle (global source chunk ^= (row>>1)&3,
// ds_read chunk = fq ^ ((fr>>1)&3)); LDS dest stays linear (gload_lds constraint).
// __launch_bounds__(256,2): cap unified VGPR+AGPR at 256 -> 2 blocks/CU.
template<bool LORA, bool F32OUT>
__global__ __launch_bounds__(256, 2) void k_gemm(const u16* __restrict__ A,
                                                 const u16* __restrict__ Bw,
                                                 float* __restrict__ Cf,
                                                 u16* __restrict__ Cb,
                                                 const float* __restrict__ T,
                                                 const float* __restrict__ WB) {
  constexpr int K = 4096, N = 4096;
  __shared__ union {
    u16   ab[2][128 * 32];   // [0]=A tile, [1]=B tile (8 KB each)
    float lr[2][128 * 16];   // epilogue: [0]=T rows, [1]=WB rows (8 KB each)
  } sm;
  const int tid = threadIdx.x;
  const int w = tid >> 6, l = tid & 63;
  const int wr = w >> 1, wc = w & 1;
  const int fr = l & 15, fq = l >> 4;
  const int bid = blockIdx.x;
  const int swz = (bid & 7) * 128 + (bid >> 3);       // XCD swizzle
  const int m0 = (swz >> 5) << 7;
  const int n0 = (swz & 31) << 7;
  const int c0 = tid, c1 = tid + 256;
  // staging: thread chunk c -> LDS row c>>2, linear chunk c&3; global chunk pre-swizzled
  const int chswz = (((tid & 3) ^ ((tid >> 3) & 3)) * 8);   // same for c0 and c1 (256%8==0)
  const u16* Ab0 = A + (size_t)(m0 + (c0 >> 2)) * K + chswz;
  const u16* Ab1 = A + (size_t)(m0 + (c1 >> 2)) * K + chswz;
  const u16* Bb0 = Bw + (size_t)(n0 + (c0 >> 2)) * K + chswz;
  const u16* Bb1 = Bw + (size_t)(n0 + (c1 >> 2)) * K + chswz;
  u16* la0 = &sm.ab[0][c0 * 8];
  u16* la1 = &sm.ab[0][c1 * 8];
  u16* lb0 = &sm.ab[1][c0 * 8];
  u16* lb1 = &sm.ab[1][c1 * 8];
  f32x4 acc[4][4];
  #pragma unroll
  for (int i = 0; i < 4; i++)
    #pragma unroll
    for (int j = 0; j < 4; j++) acc[i][j] = (f32x4){0.f, 0.f, 0.f, 0.f};
  const int ar = wr * 64 + fr, br = wc * 64 + fr;
  // read-side swizzled chunk: fq ^ s(row); s(row)=(row>>1)&3 = (fr>>1)&3 for all frags
  const int kcs = (fq ^ ((fr >> 1) & 3)) * 8;
  for (int kt = 0; kt < K; kt += 32) {
    gload16(Ab0 + kt, la0);
    gload16(Ab1 + kt, la1);
    gload16(Bb0 + kt, lb0);
    gload16(Bb1 + kt, lb1);
    __syncthreads();
    bf16x8 af[4], bv[4];
    #pragma unroll
    for (int i = 0; i < 4; i++) af[i] = *(const bf16x8*)&sm.ab[0][(ar + i * 16) * 32 + kcs];
    #pragma unroll
    for (int j = 0; j < 4; j++) bv[j] = *(const bf16x8*)&sm.ab[1][(br + j * 16) * 32 + kcs];
    #pragma unroll
    for (int i = 0; i < 4; i++)
      #pragma unroll
      for (int j = 0; j < 4; j++)
        acc[i][j] = __builtin_amdgcn_mfma_f32_16x16x32_bf16(af[i], bv[j], acc[i][j], 0, 0, 0);
    __syncthreads();
  }
  if (LORA) {
    #pragma unroll
    for (int i = 0; i < 2; i++) {
      int e = (tid + 256 * i) * 4;
      int r = e >> 4, cc = e & 15;
      *(float4*)&sm.lr[0][r * 16 + cc] = *(const float4*)&T[(m0 + r) * 16 + cc];
      *(float4*)&sm.lr[1][r * 16 + cc] = *(const float4*)&WB[(n0 + r) * 16 + cc];
    }
    __syncthreads();
  }
  #pragma unroll
  for (int i = 0; i < 4; i++) {
    #pragma unroll
    for (int j = 0; j < 4; j++) {
      const int row = wr * 64 + i * 16 + fq * 4;
      const int col = wc * 64 + j * 16 + fr;
      #pragma unroll
      for (int jj = 0; jj < 4; jj++) {
        float v = acc[i][j][jj];
        if (LORA) {
          const float* trp = &sm.lr[0][(row + jj) * 16];
          const float* wbp = &sm.lr[1][col * 16];
          float d = 0.f;
          #pragma unroll
          for (int r = 0; r < 16; r++) d += trp[r] * wbp[r];
          v += 2.0f * d;
        }
        if (F32OUT) Cf[(size_t)(m0 + row + jj) * N + (n0 + col)] = v;
        else        Cb[(size_t)(m0 + row + jj) * N + (n0 + col)] = f2b(v);
      }
    }
  }
}

// ---------------- RoPE both tensors: (b,s,h,d)bf16 -> (b,h,s,d)bf16 ------------------
// blocks [0,16384) = Q (scale 1/sqrt(HD)), [16384,32768) = K (scale 1)
__global__ __launch_bounds__(256) void k_rope2(const u16* __restrict__ qin,
                                               const u16* __restrict__ kin,
                                               u16* __restrict__ qout,
                                               u16* __restrict__ kout,
                                               const float* __restrict__ fc,
                                               const float* __restrict__ fs) {
  const int sel = blockIdx.x >> 14;
  const u16* in  = sel ? kin  : qin;
  u16*       out = sel ? kout : qout;
  const float scale = sel ? 1.0f : 0.08838834764831845f;
  const int tid = (blockIdx.x & 16383) * 256 + threadIdx.x;   // B*H*S*32 threads
  const int c4 = tid & 31;
  const int s  = (tid >> 5) & 1023;
  const int h  = (tid >> 15) & 31;
  const int b  = tid >> 20;
  const ushort4 v = *(const ushort4*)&in[(((size_t)(b * 1024 + s) * 32 + h) * 128) + c4 * 4];
  const float2 c = *(const float2*)&fc[s * 64 + c4 * 2];
  const float2 sn = *(const float2*)&fs[s * 64 + c4 * 2];
  float vx = b2f(v.x), vy = b2f(v.y), vz = b2f(v.z), vw = b2f(v.w);
  float o0 = (vx * c.x - vy * sn.x) * scale;
  float o1 = (vx * sn.x + vy * c.x) * scale;
  float o2 = (vz * c.y - vw * sn.y) * scale;
  float o3 = (vz * sn.y + vw * c.y) * scale;
  uint2 o;
  o.x = (u32)f2b(o0) | ((u32)f2b(o1) << 16);
  o.y = (u32)f2b(o2) | ((u32)f2b(o3) << 16);
  *(uint2*)&out[(((size_t)(b * 32 + h) * 1024 + s) * 128) + c4 * 4] = o;
}

// ---- fused: V transpose (b,s,h,d)->(b,h,d,s) [blocks 0..16383]  +  wo fp32->bf16
//      convert [blocks 16384..24575] ----
__global__ __launch_bounds__(256) void k_vt_cvt(const u16* __restrict__ Vb,
                                                u16* __restrict__ vt,
                                                const float* __restrict__ wo,
                                                u16* __restrict__ wo_bf) {
  __shared__ u16 tile[32][36];
  const int bid = blockIdx.x;
  const int t = threadIdx.x;
  if (bid < 16384) {                     // V transpose: B*H*(S/32)*(HD/32) tiles
    const int dt = bid & 3;
    const int st = (bid >> 2) & 31;
    const int bh = bid >> 7;
    const int r = t >> 3, c4 = (t & 7) * 4;
    const ushort4 v = *(const ushort4*)
        &Vb[((size_t)((bh >> 5) * 1024 + st * 32 + r) * 32 + (bh & 31)) * 128 + dt * 32 + c4];
    tile[r][c4] = v.x; tile[r][c4 + 1] = v.y; tile[r][c4 + 2] = v.z; tile[r][c4 + 3] = v.w;
    __syncthreads();
    uint2 o;
    o.x = (u32)tile[c4][r]     | ((u32)tile[c4 + 1][r] << 16);
    o.y = (u32)tile[c4 + 2][r] | ((u32)tile[c4 + 3][r] << 16);
    *(uint2*)&vt[((size_t)bh * 128 + dt * 32 + r) * 1024 + st * 32 + c4] = o;
  } else {                               // wo convert: 8192 blocks x 256 thr x 8 elems
    size_t i = (size_t)(bid - 16384) * 256 + t;
    const float4* s = (const float4*)wo + i * 2;
    float4 a = s[0], b = s[1];
    uint4 o;
    o.x = (u32)f2b(a.x) | ((u32)f2b(a.y) << 16);
    o.y = (u32)f2b(a.z) | ((u32)f2b(a.w) << 16);
    o.z = (u32)f2b(b.x) | ((u32)f2b(b.y) << 16);
    o.w = (u32)f2b(b.z) | ((u32)f2b(b.w) << 16);
    ((uint4*)wo_bf)[i] = o;
  }
}

// ---------------- flash attention: 1 wave = 16 q-rows, causal, online softmax -------
__global__ __launch_bounds__(64) void k_attn(const u16* __restrict__ qb,
                                             const u16* __restrict__ kb,
                                             const u16* __restrict__ vt,
                                             u16* __restrict__ ob) {
  __shared__ u16 P[16 * 32];
  const int bid = blockIdx.x;            // B*H*(S/16) = 8192
  const int qt = bid & 63;
  const int bh = bid >> 6;
  const int q0 = qt * 16;
  const int l = threadIdx.x;
  const int c = l & 15, g = l >> 4;
  const u16* qbase = qb + (size_t)bh * (S_ * HD_);
  const u16* kbase = kb + (size_t)bh * (S_ * HD_);
  const u16* vbase = vt + (size_t)bh * (HD_ * S_);
  bf16x8 qf[4];
  #pragma unroll
  for (int ks = 0; ks < 4; ks++)
    qf[ks] = *(const bf16x8*)&qbase[(q0 + c) * 128 + ks * 32 + g * 8];
  f32x4 accO[8];
  #pragma unroll
  for (int d = 0; d < 8; d++) accO[d] = (f32x4){0.f, 0.f, 0.f, 0.f};
  float mrun[4] = {-1e30f, -1e30f, -1e30f, -1e30f};
  float lrun[4] = {0.f, 0.f, 0.f, 0.f};
  const int nkb = (q0 + 47) >> 5;
  for (int kbi = 0; kbi < nkb; kbi++) {
    const int k0 = kbi * 32;
    f32x4 s0 = (f32x4){0.f, 0.f, 0.f, 0.f}, s1 = (f32x4){0.f, 0.f, 0.f, 0.f};
    #pragma unroll
    for (int ks = 0; ks < 4; ks++) {
      bf16x8 b0 = *(const bf16x8*)&kbase[(k0 + c) * 128 + ks * 32 + g * 8];
      bf16x8 b1 = *(const bf16x8*)&kbase[(k0 + 16 + c) * 128 + ks * 32 + g * 8];
      s0 = __builtin_amdgcn_mfma_f32_16x16x32_bf16(qf[ks], b0, s0, 0, 0, 0);
      s1 = __builtin_amdgcn_mfma_f32_16x16x32_bf16(qf[ks], b1, s1, 0, 0, 0);
    }
    if (kbi == nkb - 1) {           // only the last block can be causally partial
      #pragma unroll
      for (int j = 0; j < 4; j++) {
        int q = q0 + g * 4 + j;
        if (k0 + c > q)      s0[j] = -1e9f;
        if (k0 + 16 + c > q) s1[j] = -1e9f;
      }
    }
    float pv0[4], pv1[4], corr[4];
    #pragma unroll
    for (int j = 0; j < 4; j++) {
      float mx = fmaxf(s0[j], s1[j]);
      #pragma unroll
      for (int off = 8; off; off >>= 1) mx = fmaxf(mx, __shfl_xor(mx, off, 16));
      float mn = fmaxf(mrun[j], mx);
      corr[j] = __expf(mrun[j] - mn);
      mrun[j] = mn;
      float p0 = __expf(s0[j] - mn);
      float p1 = __expf(s1[j] - mn);
      float rs = p0 + p1;
      #pragma unroll
      for (int off = 8; off; off >>= 1) rs += __shfl_xor(rs, off, 16);
      lrun[j] = lrun[j] * corr[j] + rs;
      pv0[j] = p0; pv1[j] = p1;
    }
    __syncthreads();                 // prior iteration's P reads drained
    #pragma unroll
    for (int j = 0; j < 4; j++) {
      P[(g * 4 + j) * 32 + c]      = f2b(pv0[j]);
      P[(g * 4 + j) * 32 + 16 + c] = f2b(pv1[j]);
    }
    __syncthreads();                 // P visible across lanes
    bf16x8 pa = *(const bf16x8*)&P[c * 32 + g * 8];
    #pragma unroll
    for (int d = 0; d < 8; d++) {
      #pragma unroll
      for (int j = 0; j < 4; j++) accO[d][j] *= corr[j];
    }
    #pragma unroll
    for (int d = 0; d < 8; d++) {
      bf16x8 vf = *(const bf16x8*)&vbase[(d * 16 + c) * 1024 + k0 + g * 8];
      accO[d] = __builtin_amdgcn_mfma_f32_16x16x32_bf16(pa, vf, accO[d], 0, 0, 0);
    }
  }
  float inv[4];
  #pragma unroll
  for (int j = 0; j < 4; j++) inv[j] = 1.0f / lrun[j];
  #pragma unroll
  for (int d = 0; d < 8; d++) {
    #pragma unroll
    for (int j = 0; j < 4; j++) {
      float val = accO[d][j] * inv[j];
      ob[(size_t)((bh >> 5) * 1024 + q0 + g * 4 + j) * 4096 + (bh & 31) * 128 + d * 16 + c]
          = f2b(val);
    }
  }
}

// =====================================================================================
extern "C" void kernel_launch(void* const* d_in, const int* in_sizes, int n_in,
                              void* d_out, int out_size, void* d_ws, size_t ws_size,
                              hipStream_t stream) {
  const float* x    = (const float*)d_in[0];
  const float* wq_w = (const float*)d_in[1];
  const float* wq_a = (const float*)d_in[2];
  const float* wq_b = (const float*)d_in[3];
  const float* wk_w = (const float*)d_in[4];
  const float* wv_w = (const float*)d_in[5];
  const float* wv_a = (const float*)d_in[6];
  const float* wv_b = (const float*)d_in[7];
  const float* wo_w = (const float*)d_in[8];
  const float* fc   = (const float*)d_in[9];
  const float* fs   = (const float*)d_in[10];
  // d_in[11] = mask (causal, applied analytically), d_in[12] = start_pos (0)

  // 7 x 32MB slots, time-aliased along the serial stream order (+ 2 small fp32 bufs)
  char* p = (char*)d_ws;
  const size_t SZ_BF = (size_t)M_ * D_ * 2;   // 32 MB
  u16* s0 = (u16*)(p + 0 * SZ_BF);   // x_bf   -> wo_bf
  u16* s1 = (u16*)(p + 1 * SZ_BF);   // wq_bf  -> att_bf
  u16* s2 = (u16*)(p + 2 * SZ_BF);   // wk_bf  -> q_bf
  u16* s3 = (u16*)(p + 3 * SZ_BF);   // wv_bf  -> k_bf
  u16* s4 = (u16*)(p + 4 * SZ_BF);   // Qb     -> v_t
  u16* s5 = (u16*)(p + 5 * SZ_BF);   // Kb
  u16* s6 = (u16*)(p + 6 * SZ_BF);   // Vb
  float* t_q = (float*)(p + 7 * SZ_BF);
  float* t_v = t_q + (size_t)M_ * 16;

  // 1. bf16 conversions (x, wq, wk, wv) in one dispatch
  k_cvt4<<<32768, 256, 0, stream>>>(x, wq_w, wk_w, wv_w, s0, s1, s2, s3);

  // 2. LoRA intermediates (fp32 exact, from fp32 x)
  k_lora_t<<<128, 256, 0, stream>>>(x, wq_a, wv_a, t_q, t_v);

  // 3. projections (bf16 MFMA, bf16 out; LoRA rank-16 fp32 epilogue for Q and V)
  k_gemm<true,  false><<<1024, 256, 0, stream>>>(s0, s1, nullptr, s4, t_q, wq_b);        // Qb
  k_gemm<false, false><<<1024, 256, 0, stream>>>(s0, s2, nullptr, s5, nullptr, nullptr); // Kb
  k_gemm<true,  false><<<1024, 256, 0, stream>>>(s0, s3, nullptr, s6, t_v, wv_b);        // Vb

  // 4. RoPE Q (+1/sqrt(HD)) and K -> (b,h,s,d) bf16, one dispatch
  k_rope2<<<32768, 256, 0, stream>>>(s4, s5, s2, s3, fc, fs);  // Qb->q_bf(s2), Kb->k_bf(s3)

  // 5. V -> (b,h,d,s) bf16 (into s4; Qb dead)  +  wo convert (into s0; x_bf dead)
  k_vt_cvt<<<24576, 256, 0, stream>>>(s6, s4, wo_w, s0);

  // 6. causal flash attention -> (b,s,h*d) bf16 (wq_bf slot s1 dead)
  k_attn<<<8192, 64, 0, stream>>>(s2, s3, s4, s1);

  // 7. output projection -> fp32 d_out
  k_gemm<false, true><<<1024, 256, 0, stream>>>(s1, s0, (float*)d_out, nullptr, nullptr, nullptr);
}

// Round 6
// 2060.507 us; speedup vs baseline: 1.6867x; 1.2115x over previous
//
#include <hip/hip_runtime.h>

typedef unsigned short u16;
typedef unsigned int   u32;

typedef __bf16 bf16x8 __attribute__((ext_vector_type(8)));
typedef float  f32x4  __attribute__((ext_vector_type(4)));

typedef __attribute__((address_space(1))) const u32* gas_u32;
typedef __attribute__((address_space(3))) u32*       las_u32;

#define B_  4
#define S_  1024
#define D_  4096
#define H_  32
#define HD_ 128
#define M_  4096

__device__ __forceinline__ void gload16(const void* g, void* l) {
  __builtin_amdgcn_global_load_lds((gas_u32)g, (las_u32)l, 16, 0, 0);
}

__device__ __forceinline__ u16 f2b(float x) {
  u32 u = __float_as_uint(x);
  u32 r = (u + 0x7fffu + ((u >> 16) & 1u)) >> 16;
  return (u16)r;
}
__device__ __forceinline__ float b2f(u16 x) {
  return __uint_as_float((u32)x << 16);
}

// ---------------- fp32 -> bf16 convert: 4 tensors in one dispatch ----------------
__global__ __launch_bounds__(256) void k_cvt4(const float* __restrict__ sa,
                                              const float* __restrict__ sb,
                                              const float* __restrict__ sc,
                                              const float* __restrict__ sd,
                                              u16* __restrict__ da,
                                              u16* __restrict__ db,
                                              u16* __restrict__ dc,
                                              u16* __restrict__ dd) {
  const int sel = blockIdx.x >> 13;          // 4 x 8192 blocks
  const float* src = sel == 0 ? sa : sel == 1 ? sb : sel == 2 ? sc : sd;
  u16*         dst = sel == 0 ? da : sel == 1 ? db : sel == 2 ? dc : dd;
  size_t i = (size_t)(blockIdx.x & 8191) * 256 + threadIdx.x;
  const float4* s = (const float4*)src + i * 2;
  float4 a = s[0], b = s[1];
  uint4 o;
  o.x = (u32)f2b(a.x) | ((u32)f2b(a.y) << 16);
  o.y = (u32)f2b(a.z) | ((u32)f2b(a.w) << 16);
  o.z = (u32)f2b(b.x) | ((u32)f2b(b.y) << 16);
  o.w = (u32)f2b(b.z) | ((u32)f2b(b.w) << 16);
  ((uint4*)dst)[i] = o;
}

// ---------------- LoRA intermediates: t_q = x@wq_a^T, t_v = x@wv_a^T (fp32 exact) ----
__global__ __launch_bounds__(256) void k_lora_t(const float* __restrict__ x,
                                                const float* __restrict__ wqa,
                                                const float* __restrict__ wva,
                                                float* __restrict__ tq,
                                                float* __restrict__ tv) {
  __shared__ float xs[32][136];
  __shared__ float was[32][136];
  const int tid = threadIdx.x;
  const int m0 = blockIdx.x * 32;
  const int mr = tid >> 3, rg = tid & 7;
  float a0 = 0.f, a1 = 0.f, a2 = 0.f, a3 = 0.f;
  for (int kc = 0; kc < 4096; kc += 128) {
    #pragma unroll
    for (int i = 0; i < 4; i++) {
      int e = (tid + 256 * i) * 4;
      int row = e >> 7, col = e & 127;
      *(float4*)&xs[row][col] = *(const float4*)&x[(size_t)(m0 + row) * 4096 + kc + col];
      const float* wsrc = (row < 16) ? &wqa[row * 4096 + kc + col]
                                     : &wva[(row - 16) * 4096 + kc + col];
      *(float4*)&was[row][col] = *(const float4*)wsrc;
    }
    __syncthreads();
    #pragma unroll 8
    for (int ks = 0; ks < 32; ks++) {
      float4 xv = *(float4*)&xs[mr][ks * 4];
      float4 w0 = *(float4*)&was[rg][ks * 4];
      float4 w1 = *(float4*)&was[rg + 8][ks * 4];
      float4 w2 = *(float4*)&was[rg + 16][ks * 4];
      float4 w3 = *(float4*)&was[rg + 24][ks * 4];
      a0 += xv.x * w0.x + xv.y * w0.y + xv.z * w0.z + xv.w * w0.w;
      a1 += xv.x * w1.x + xv.y * w1.y + xv.z * w1.z + xv.w * w1.w;
      a2 += xv.x * w2.x + xv.y * w2.y + xv.z * w2.z + xv.w * w2.w;
      a3 += xv.x * w3.x + xv.y * w3.y + xv.z * w3.z + xv.w * w3.w;
    }
    __syncthreads();
  }
  tq[(m0 + mr) * 16 + rg]     = a0;
  tq[(m0 + mr) * 16 + rg + 8] = a1;
  tv[(m0 + mr) * 16 + rg]     = a2;
  tv[(m0 + mr) * 16 + rg + 8] = a3;
}

// ===================== 256x256 8-phase GEMM (T2+T3+T4+T5 template) ===================
// C(4096x4096) = A(bf16) @ B(bf16)^T [+ 2*T@WB^T].  BK=64, 512 thr = 8 waves (2Mx4N),
// per-wave 128x64 out (acc[8][4] f32x4 = 128 AGPR). LDS 128KB = 2 bufs x (A 32KB + B
// 32KB), buf0 = even K-tiles, buf1 = odd. XOR-8 chunk swizzle (both-sides: staged
// global source chunk = c ^ (ldsrow&7), ds_read chunk = want ^ (ldsrow&7)) ->
// conflict-free ds_read_b128. Raw s_barrier (no vmcnt drain), vmcnt(4) at ph4/ph8.
// A LDS row remap: h-groups contiguous (m -> h*128 + (m>>7)*64 + (m&63)), B: x-groups
// (n -> x*128 + (n>>6)*32 + (n&31)) so 8KB gload segments align with consumption.
#define BAR() do { __builtin_amdgcn_sched_barrier(0); __builtin_amdgcn_s_barrier(); \
                   __builtin_amdgcn_sched_barrier(0); } while (0)
#define VMCNT4() asm volatile("s_waitcnt vmcnt(4)" ::: "memory")

#define STAGE(buf, tens, s, t) \
  gload16(((tens) ? Bw : A) + ((tens) ? offB[s] : offA[s]) + (t) * 64, \
          &lds.g[(buf) * 32768 + (tens) * 16384 + (s) * 4096 + tid * 8])

#define LDA(buf, h) do { \
  _Pragma("unroll") for (int i_ = 0; i_ < 4; i_++) { \
    const int r_ = ((h) * 128 + wm * 64 + i_ * 16 + fr) * 64; \
    a[i_][0] = *(const bf16x8*)&lds.g[(buf) * 32768 + r_ + ck0]; \
    a[i_][1] = *(const bf16x8*)&lds.g[(buf) * 32768 + r_ + ck1]; } } while (0)

#define LDB(buf, x, bb) do { \
  _Pragma("unroll") for (int j_ = 0; j_ < 2; j_++) { \
    const int r_ = ((x) * 128 + wn * 32 + j_ * 16 + fr) * 64; \
    bb[j_][0] = *(const bf16x8*)&lds.g[(buf) * 32768 + 16384 + r_ + ck0]; \
    bb[j_][1] = *(const bf16x8*)&lds.g[(buf) * 32768 + 16384 + r_ + ck1]; } } while (0)

#define DO_MFMA(h, x, bb) do { \
  __builtin_amdgcn_s_setprio(1); \
  _Pragma("unroll") for (int i_ = 0; i_ < 4; i_++) \
    _Pragma("unroll") for (int j_ = 0; j_ < 2; j_++) { \
      acc[(h) * 4 + i_][(x) * 2 + j_] = __builtin_amdgcn_mfma_f32_16x16x32_bf16( \
          a[i_][0], bb[j_][0], acc[(h) * 4 + i_][(x) * 2 + j_], 0, 0, 0); \
      acc[(h) * 4 + i_][(x) * 2 + j_] = __builtin_amdgcn_mfma_f32_16x16x32_bf16( \
          a[i_][1], bb[j_][1], acc[(h) * 4 + i_][(x) * 2 + j_], 0, 0, 0); } \
  __builtin_amdgcn_s_setprio(0); } while (0)

template<bool LORA, bool F32OUT>
__global__ __launch_bounds__(512, 2) void k_gemm(const u16* __restrict__ A,
                                                 const u16* __restrict__ Bw,
                                                 float* __restrict__ Cf,
                                                 u16* __restrict__ Cb,
                                                 const float* __restrict__ T,
                                                 const float* __restrict__ WB) {
  constexpr int K = 4096, N = 4096;
  __shared__ union {
    u16 g[2 * 2 * 16384];                       // 128 KB: [buf][A/B][16384 u16]
    struct { float t[256][20]; float w[256][20]; } ep;   // LoRA epilogue (40 KB)
  } lds;
  const int tid = threadIdx.x;
  const int lane = tid & 63, wid = tid >> 6;
  const int fr = lane & 15, fq = lane >> 4;
  const int wm = wid >> 2, wn = wid & 3;
  const int swz = (blockIdx.x & 7) * 32 + (blockIdx.x >> 3);   // XCD swizzle (256%8==0)
  const int m0 = (swz >> 4) << 8;
  const int n0 = (swz & 15) << 8;

  // staging constants: thread -> (segment row u, swizzled global chunk cg)
  const int u = tid >> 3;
  const int cg = (tid & 7) ^ (u & 7);
  u32 offA[4], offB[4];
  offA[0] = (u32)(m0 + u) * K + cg * 8;
  offA[1] = (u32)(m0 + u + 128) * K + cg * 8;
  offA[2] = (u32)(m0 + u + 64) * K + cg * 8;
  offA[3] = (u32)(m0 + u + 192) * K + cg * 8;
  const int ub = (u & 31), uh = (u >> 5);                  // B row decode
  offB[0] = (u32)(n0 + ub + uh * 64) * K + cg * 8;
  offB[1] = (u32)(n0 + ub + 128 + uh * 64) * K + cg * 8;
  offB[2] = (u32)(n0 + ub + uh * 64 + 32) * K + cg * 8;
  offB[3] = (u32)(n0 + ub + 128 + uh * 64 + 32) * K + cg * 8;

  // ds_read swizzled chunk offsets (elements) for kk=0,1
  const int ck0 = ((((fr >> 2) & 1) << 2) | (fq ^ (fr & 3))) * 8;
  const int ck1 = (((1 ^ ((fr >> 2) & 1)) << 2) | (fq ^ (fr & 3))) * 8;

  f32x4 acc[8][4];
  #pragma unroll
  for (int i = 0; i < 8; i++)
    #pragma unroll
    for (int j = 0; j < 4; j++) acc[i][j] = (f32x4){0.f, 0.f, 0.f, 0.f};
  bf16x8 a[4][2], b0[2][2], b1[2][2];

  // prologue: tile0 full (8 segs, buf0), tile1 segs A0,A1,B0,B1 (buf1)
  STAGE(0, 0, 0, 0); STAGE(0, 0, 1, 0); STAGE(0, 1, 0, 0); STAGE(0, 1, 1, 0);
  STAGE(0, 0, 2, 0); STAGE(0, 0, 3, 0); STAGE(0, 1, 2, 0); STAGE(0, 1, 3, 0);
  STAGE(1, 0, 0, 1); STAGE(1, 0, 1, 1); STAGE(1, 1, 0, 1); STAGE(1, 1, 1, 1);
  VMCNT4();
  BAR();

  for (int it = 0; it < 32; ++it) {
    const int t1 = (2 * it + 1) & 63, t2 = (2 * it + 2) & 63, t3 = (2 * it + 3) & 63;
    // PH1: buf0 reads A-h0 + B-x0 (tile 2it); stage buf1 A2,A3 (tile t1)
    LDA(0, 0); LDB(0, 0, b0);
    STAGE(1, 0, 2, t1); STAGE(1, 0, 3, t1);
    BAR(); DO_MFMA(0, 0, b0); BAR();
    // PH2: read B-x1; stage buf1 B2,B3 (t1)
    LDB(0, 1, b1);
    STAGE(1, 1, 2, t1); STAGE(1, 1, 3, t1);
    BAR(); DO_MFMA(0, 1, b1); BAR();
    // PH3: read A-h1; stage buf0 A0,A1 (t2)
    LDA(0, 1);
    STAGE(0, 0, 0, t2); STAGE(0, 0, 1, t2);
    BAR(); DO_MFMA(1, 0, b0); BAR();
    // PH4: stage buf0 B0,B1 (t2); counted vmcnt
    STAGE(0, 1, 0, t2); STAGE(0, 1, 1, t2);
    VMCNT4();
    BAR(); DO_MFMA(1, 1, b1); BAR();
    // PH5: buf1 reads A-h0 + B-x0 (tile 2it+1); stage buf0 A2,A3 (t2)
    LDA(1, 0); LDB(1, 0, b0);
    STAGE(0, 0, 2, t2); STAGE(0, 0, 3, t2);
    BAR(); DO_MFMA(0, 0, b0); BAR();
    // PH6: read B-x1; stage buf0 B2,B3 (t2)
    LDB(1, 1, b1);
    STAGE(0, 1, 2, t2); STAGE(0, 1, 3, t2);
    BAR(); DO_MFMA(0, 1, b1); BAR();
    // PH7: read A-h1; stage buf1 A0,A1 (t3)
    LDA(1, 1);
    STAGE(1, 0, 0, t3); STAGE(1, 0, 1, t3);
    BAR(); DO_MFMA(1, 0, b0); BAR();
    // PH8: stage buf1 B0,B1 (t3); counted vmcnt
    STAGE(1, 1, 0, t3); STAGE(1, 1, 1, t3);
    VMCNT4();
    BAR(); DO_MFMA(1, 1, b1); BAR();
  }

  __syncthreads();                 // full drain (also lands wrapped dangling stages)
  if (LORA) {
    const int row = tid >> 1, hf = (tid & 1) * 8;
    *(float4*)&lds.ep.t[row][hf]     = *(const float4*)&T[(m0 + row) * 16 + hf];
    *(float4*)&lds.ep.t[row][hf + 4] = *(const float4*)&T[(m0 + row) * 16 + hf + 4];
    *(float4*)&lds.ep.w[row][hf]     = *(const float4*)&WB[(n0 + row) * 16 + hf];
    *(float4*)&lds.ep.w[row][hf + 4] = *(const float4*)&WB[(n0 + row) * 16 + hf + 4];
    __syncthreads();
  }

  float wc[4][16];                 // per-thread 4 output cols' WB rows
  if (LORA) {
    #pragma unroll
    for (int q = 0; q < 4; q++) {
      const int coll = wn * 64 + (q >> 1) * 32 + (q & 1) * 16 + fr;
      #pragma unroll
      for (int r4 = 0; r4 < 4; r4++)
        *(float4*)&wc[q][r4 * 4] = *(float4*)&lds.ep.w[coll][r4 * 4];
    }
  }
  #pragma unroll
  for (int h = 0; h < 2; h++)
    #pragma unroll
    for (int i = 0; i < 4; i++)
      #pragma unroll
      for (int jj = 0; jj < 4; jj++) {
        const int rowl = wm * 128 + h * 64 + i * 16 + fq * 4 + jj;
        float tr[16];
        if (LORA) {
          #pragma unroll
          for (int r4 = 0; r4 < 4; r4++)
            *(float4*)&tr[r4 * 4] = *(float4*)&lds.ep.t[rowl][r4 * 4];
        }
        #pragma unroll
        for (int q = 0; q < 4; q++) {
          float v = acc[h * 4 + i][q][jj];
          if (LORA) {
            float d = 0.f;
            #pragma unroll
            for (int r = 0; r < 16; r++) d += tr[r] * wc[q][r];
            v += 2.0f * d;
          }
          const int col = n0 + wn * 64 + (q >> 1) * 32 + (q & 1) * 16 + fr;
          if (F32OUT) Cf[(size_t)(m0 + rowl) * N + col] = v;
          else        Cb[(size_t)(m0 + rowl) * N + col] = f2b(v);
        }
      }
}

// ---------------- RoPE both tensors: (b,s,h,d)bf16 -> (b,h,s,d)bf16 ------------------
__global__ __launch_bounds__(256) void k_rope2(const u16* __restrict__ qin,
                                               const u16* __restrict__ kin,
                                               u16* __restrict__ qout,
                                               u16* __restrict__ kout,
                                               const float* __restrict__ fc,
                                               const float* __restrict__ fs) {
  const int sel = blockIdx.x >> 14;
  const u16* in  = sel ? kin  : qin;
  u16*       out = sel ? kout : qout;
  const float scale = sel ? 1.0f : 0.08838834764831845f;
  const int tid = (blockIdx.x & 16383) * 256 + threadIdx.x;   // B*H*S*32 threads
  const int c4 = tid & 31;
  const int s  = (tid >> 5) & 1023;
  const int h  = (tid >> 15) & 31;
  const int b  = tid >> 20;
  const ushort4 v = *(const ushort4*)&in[(((size_t)(b * 1024 + s) * 32 + h) * 128) + c4 * 4];
  const float2 c = *(const float2*)&fc[s * 64 + c4 * 2];
  const float2 sn = *(const float2*)&fs[s * 64 + c4 * 2];
  float vx = b2f(v.x), vy = b2f(v.y), vz = b2f(v.z), vw = b2f(v.w);
  float o0 = (vx * c.x - vy * sn.x) * scale;
  float o1 = (vx * sn.x + vy * c.x) * scale;
  float o2 = (vz * c.y - vw * sn.y) * scale;
  float o3 = (vz * sn.y + vw * c.y) * scale;
  uint2 o;
  o.x = (u32)f2b(o0) | ((u32)f2b(o1) << 16);
  o.y = (u32)f2b(o2) | ((u32)f2b(o3) << 16);
  *(uint2*)&out[(((size_t)(b * 32 + h) * 1024 + s) * 128) + c4 * 4] = o;
}

// ---- fused: V transpose (b,s,h,d)->(b,h,d,s) [blocks 0..16383]  +  wo fp32->bf16 ----
__global__ __launch_bounds__(256) void k_vt_cvt(const u16* __restrict__ Vb,
                                                u16* __restrict__ vt,
                                                const float* __restrict__ wo,
                                                u16* __restrict__ wo_bf) {
  __shared__ u16 tile[32][36];
  const int bid = blockIdx.x;
  const int t = threadIdx.x;
  if (bid < 16384) {
    const int dt = bid & 3;
    const int st = (bid >> 2) & 31;
    const int bh = bid >> 7;
    const int r = t >> 3, c4 = (t & 7) * 4;
    const ushort4 v = *(const ushort4*)
        &Vb[((size_t)((bh >> 5) * 1024 + st * 32 + r) * 32 + (bh & 31)) * 128 + dt * 32 + c4];
    tile[r][c4] = v.x; tile[r][c4 + 1] = v.y; tile[r][c4 + 2] = v.z; tile[r][c4 + 3] = v.w;
    __syncthreads();
    uint2 o;
    o.x = (u32)tile[c4][r]     | ((u32)tile[c4 + 1][r] << 16);
    o.y = (u32)tile[c4 + 2][r] | ((u32)tile[c4 + 3][r] << 16);
    *(uint2*)&vt[((size_t)bh * 128 + dt * 32 + r) * 1024 + st * 32 + c4] = o;
  } else {
    size_t i = (size_t)(bid - 16384) * 256 + t;
    const float4* s = (const float4*)wo + i * 2;
    float4 a = s[0], b = s[1];
    uint4 o;
    o.x = (u32)f2b(a.x) | ((u32)f2b(a.y) << 16);
    o.y = (u32)f2b(a.z) | ((u32)f2b(a.w) << 16);
    o.z = (u32)f2b(b.x) | ((u32)f2b(b.y) << 16);
    o.w = (u32)f2b(b.z) | ((u32)f2b(b.w) << 16);
    ((uint4*)wo_bf)[i] = o;
  }
}

// ---------------- flash attention: 1 wave = 16 q-rows, causal, online softmax -------
__global__ __launch_bounds__(64) void k_attn(const u16* __restrict__ qb,
                                             const u16* __restrict__ kb,
                                             const u16* __restrict__ vt,
                                             u16* __restrict__ ob) {
  __shared__ u16 P[16 * 32];
  const int bid = blockIdx.x;            // B*H*(S/16) = 8192
  const int qt = bid & 63;
  const int bh = bid >> 6;
  const int q0 = qt * 16;
  const int l = threadIdx.x;
  const int c = l & 15, g = l >> 4;
  const u16* qbase = qb + (size_t)bh * (S_ * HD_);
  const u16* kbase = kb + (size_t)bh * (S_ * HD_);
  const u16* vbase = vt + (size_t)bh * (HD_ * S_);
  bf16x8 qf[4];
  #pragma unroll
  for (int ks = 0; ks < 4; ks++)
    qf[ks] = *(const bf16x8*)&qbase[(q0 + c) * 128 + ks * 32 + g * 8];
  f32x4 accO[8];
  #pragma unroll
  for (int d = 0; d < 8; d++) accO[d] = (f32x4){0.f, 0.f, 0.f, 0.f};
  float mrun[4] = {-1e30f, -1e30f, -1e30f, -1e30f};
  float lrun[4] = {0.f, 0.f, 0.f, 0.f};
  const int nkb = (q0 + 47) >> 5;
  for (int kbi = 0; kbi < nkb; kbi++) {
    const int k0 = kbi * 32;
    f32x4 s0 = (f32x4){0.f, 0.f, 0.f, 0.f}, s1 = (f32x4){0.f, 0.f, 0.f, 0.f};
    #pragma unroll
    for (int ks = 0; ks < 4; ks++) {
      bf16x8 b0 = *(const bf16x8*)&kbase[(k0 + c) * 128 + ks * 32 + g * 8];
      bf16x8 b1 = *(const bf16x8*)&kbase[(k0 + 16 + c) * 128 + ks * 32 + g * 8];
      s0 = __builtin_amdgcn_mfma_f32_16x16x32_bf16(qf[ks], b0, s0, 0, 0, 0);
      s1 = __builtin_amdgcn_mfma_f32_16x16x32_bf16(qf[ks], b1, s1, 0, 0, 0);
    }
    if (kbi == nkb - 1) {
      #pragma unroll
      for (int j = 0; j < 4; j++) {
        int q = q0 + g * 4 + j;
        if (k0 + c > q)      s0[j] = -1e9f;
        if (k0 + 16 + c > q) s1[j] = -1e9f;
      }
    }
    float pv0[4], pv1[4], corr[4];
    #pragma unroll
    for (int j = 0; j < 4; j++) {
      float mx = fmaxf(s0[j], s1[j]);
      #pragma unroll
      for (int off = 8; off; off >>= 1) mx = fmaxf(mx, __shfl_xor(mx, off, 16));
      float mn = fmaxf(mrun[j], mx);
      corr[j] = __expf(mrun[j] - mn);
      mrun[j] = mn;
      float p0 = __expf(s0[j] - mn);
      float p1 = __expf(s1[j] - mn);
      float rs = p0 + p1;
      #pragma unroll
      for (int off = 8; off; off >>= 1) rs += __shfl_xor(rs, off, 16);
      lrun[j] = lrun[j] * corr[j] + rs;
      pv0[j] = p0; pv1[j] = p1;
    }
    __syncthreads();
    #pragma unroll
    for (int j = 0; j < 4; j++) {
      P[(g * 4 + j) * 32 + c]      = f2b(pv0[j]);
      P[(g * 4 + j) * 32 + 16 + c] = f2b(pv1[j]);
    }
    __syncthreads();
    bf16x8 pa = *(const bf16x8*)&P[c * 32 + g * 8];
    #pragma unroll
    for (int d = 0; d < 8; d++) {
      #pragma unroll
      for (int j = 0; j < 4; j++) accO[d][j] *= corr[j];
    }
    #pragma unroll
    for (int d = 0; d < 8; d++) {
      bf16x8 vf = *(const bf16x8*)&vbase[(d * 16 + c) * 1024 + k0 + g * 8];
      accO[d] = __builtin_amdgcn_mfma_f32_16x16x32_bf16(pa, vf, accO[d], 0, 0, 0);
    }
  }
  float inv[4];
  #pragma unroll
  for (int j = 0; j < 4; j++) inv[j] = 1.0f / lrun[j];
  #pragma unroll
  for (int d = 0; d < 8; d++) {
    #pragma unroll
    for (int j = 0; j < 4; j++) {
      float val = accO[d][j] * inv[j];
      ob[(size_t)((bh >> 5) * 1024 + q0 + g * 4 + j) * 4096 + (bh & 31) * 128 + d * 16 + c]
          = f2b(val);
    }
  }
}

// =====================================================================================
extern "C" void kernel_launch(void* const* d_in, const int* in_sizes, int n_in,
                              void* d_out, int out_size, void* d_ws, size_t ws_size,
                              hipStream_t stream) {
  const float* x    = (const float*)d_in[0];
  const float* wq_w = (const float*)d_in[1];
  const float* wq_a = (const float*)d_in[2];
  const float* wq_b = (const float*)d_in[3];
  const float* wk_w = (const float*)d_in[4];
  const float* wv_w = (const float*)d_in[5];
  const float* wv_a = (const float*)d_in[6];
  const float* wv_b = (const float*)d_in[7];
  const float* wo_w = (const float*)d_in[8];
  const float* fc   = (const float*)d_in[9];
  const float* fs   = (const float*)d_in[10];
  // d_in[11] = mask (causal, applied analytically), d_in[12] = start_pos (0)

  // 7 x 32MB slots, time-aliased along the serial stream order (+ 2 small fp32 bufs)
  char* p = (char*)d_ws;
  const size_t SZ_BF = (size_t)M_ * D_ * 2;   // 32 MB
  u16* s0 = (u16*)(p + 0 * SZ_BF);   // x_bf   -> wo_bf
  u16* s1 = (u16*)(p + 1 * SZ_BF);   // wq_bf  -> att_bf
  u16* s2 = (u16*)(p + 2 * SZ_BF);   // wk_bf  -> q_bf
  u16* s3 = (u16*)(p + 3 * SZ_BF);   // wv_bf  -> k_bf
  u16* s4 = (u16*)(p + 4 * SZ_BF);   // Qb     -> v_t
  u16* s5 = (u16*)(p + 5 * SZ_BF);   // Kb
  u16* s6 = (u16*)(p + 6 * SZ_BF);   // Vb
  float* t_q = (float*)(p + 7 * SZ_BF);
  float* t_v = t_q + (size_t)M_ * 16;

  // 1. bf16 conversions (x, wq, wk, wv) in one dispatch
  k_cvt4<<<32768, 256, 0, stream>>>(x, wq_w, wk_w, wv_w, s0, s1, s2, s3);

  // 2. LoRA intermediates (fp32 exact, from fp32 x)
  k_lora_t<<<128, 256, 0, stream>>>(x, wq_a, wv_a, t_q, t_v);

  // 3. projections (256x256 8-phase bf16 MFMA; LoRA rank-16 fp32 epilogue for Q and V)
  k_gemm<true,  false><<<256, 512, 0, stream>>>(s0, s1, nullptr, s4, t_q, wq_b);        // Qb
  k_gemm<false, false><<<256, 512, 0, stream>>>(s0, s2, nullptr, s5, nullptr, nullptr); // Kb
  k_gemm<true,  false><<<256, 512, 0, stream>>>(s0, s3, nullptr, s6, t_v, wv_b);        // Vb

  // 4. RoPE Q (+1/sqrt(HD)) and K -> (b,h,s,d) bf16, one dispatch
  k_rope2<<<32768, 256, 0, stream>>>(s4, s5, s2, s3, fc, fs);  // Qb->q_bf(s2), Kb->k_bf(s3)

  // 5. V -> (b,h,d,s) bf16 (into s4; Qb dead)  +  wo convert (into s0; x_bf dead)
  k_vt_cvt<<<24576, 256, 0, stream>>>(s6, s4, wo_w, s0);

  // 6. causal flash attention -> (b,s,h*d) bf16 (wq_bf slot s1 dead)
  k_attn<<<8192, 64, 0, stream>>>(s2, s3, s4, s1);

  // 7. output projection -> fp32 d_out
  k_gemm<false, true><<<256, 512, 0, stream>>>(s1, s0, (float*)d_out, nullptr, nullptr, nullptr);
}

// Round 7
// 1853.294 us; speedup vs baseline: 1.8753x; 1.1118x over previous
//
#include <hip/hip_runtime.h>

typedef unsigned short u16;
typedef unsigned int   u32;

typedef __bf16 bf16x8 __attribute__((ext_vector_type(8)));
typedef float  f32x4  __attribute__((ext_vector_type(4)));

typedef __attribute__((address_space(1))) const u32* gas_u32;
typedef __attribute__((address_space(3))) u32*       las_u32;

#define B_  4
#define S_  1024
#define D_  4096
#define H_  32
#define HD_ 128
#define M_  4096

__device__ __forceinline__ void gload16(const void* g, void* l) {
  __builtin_amdgcn_global_load_lds((gas_u32)g, (las_u32)l, 16, 0, 0);
}

__device__ __forceinline__ u16 f2b(float x) {
  u32 u = __float_as_uint(x);
  u32 r = (u + 0x7fffu + ((u >> 16) & 1u)) >> 16;
  return (u16)r;
}
__device__ __forceinline__ float b2f(u16 x) {
  return __uint_as_float((u32)x << 16);
}

// ---------------- fp32 -> bf16 convert: 4 tensors in one dispatch ----------------
__global__ __launch_bounds__(256) void k_cvt4(const float* __restrict__ sa,
                                              const float* __restrict__ sb,
                                              const float* __restrict__ sc,
                                              const float* __restrict__ sd,
                                              u16* __restrict__ da,
                                              u16* __restrict__ db,
                                              u16* __restrict__ dc,
                                              u16* __restrict__ dd) {
  const int sel = blockIdx.x >> 13;          // 4 x 8192 blocks
  const float* src = sel == 0 ? sa : sel == 1 ? sb : sel == 2 ? sc : sd;
  u16*         dst = sel == 0 ? da : sel == 1 ? db : sel == 2 ? dc : dd;
  size_t i = (size_t)(blockIdx.x & 8191) * 256 + threadIdx.x;
  const float4* s = (const float4*)src + i * 2;
  float4 a = s[0], b = s[1];
  uint4 o;
  o.x = (u32)f2b(a.x) | ((u32)f2b(a.y) << 16);
  o.y = (u32)f2b(a.z) | ((u32)f2b(a.w) << 16);
  o.z = (u32)f2b(b.x) | ((u32)f2b(b.y) << 16);
  o.w = (u32)f2b(b.z) | ((u32)f2b(b.w) << 16);
  ((uint4*)dst)[i] = o;
}

// ---------------- LoRA intermediates: t_q = x@wq_a^T, t_v = x@wv_a^T (fp32 exact) ----
__global__ __launch_bounds__(256) void k_lora_t(const float* __restrict__ x,
                                                const float* __restrict__ wqa,
                                                const float* __restrict__ wva,
                                                float* __restrict__ tq,
                                                float* __restrict__ tv) {
  __shared__ float xs[32][136];
  __shared__ float was[32][136];
  const int tid = threadIdx.x;
  const int m0 = blockIdx.x * 32;
  const int mr = tid >> 3, rg = tid & 7;
  float a0 = 0.f, a1 = 0.f, a2 = 0.f, a3 = 0.f;
  for (int kc = 0; kc < 4096; kc += 128) {
    #pragma unroll
    for (int i = 0; i < 4; i++) {
      int e = (tid + 256 * i) * 4;
      int row = e >> 7, col = e & 127;
      *(float4*)&xs[row][col] = *(const float4*)&x[(size_t)(m0 + row) * 4096 + kc + col];
      const float* wsrc = (row < 16) ? &wqa[row * 4096 + kc + col]
                                     : &wva[(row - 16) * 4096 + kc + col];
      *(float4*)&was[row][col] = *(const float4*)wsrc;
    }
    __syncthreads();
    #pragma unroll 8
    for (int ks = 0; ks < 32; ks++) {
      float4 xv = *(float4*)&xs[mr][ks * 4];
      float4 w0 = *(float4*)&was[rg][ks * 4];
      float4 w1 = *(float4*)&was[rg + 8][ks * 4];
      float4 w2 = *(float4*)&was[rg + 16][ks * 4];
      float4 w3 = *(float4*)&was[rg + 24][ks * 4];
      a0 += xv.x * w0.x + xv.y * w0.y + xv.z * w0.z + xv.w * w0.w;
      a1 += xv.x * w1.x + xv.y * w1.y + xv.z * w1.z + xv.w * w1.w;
      a2 += xv.x * w2.x + xv.y * w2.y + xv.z * w2.z + xv.w * w2.w;
      a3 += xv.x * w3.x + xv.y * w3.y + xv.z * w3.z + xv.w * w3.w;
    }
    __syncthreads();
  }
  tq[(m0 + mr) * 16 + rg]     = a0;
  tq[(m0 + mr) * 16 + rg + 8] = a1;
  tv[(m0 + mr) * 16 + rg]     = a2;
  tv[(m0 + mr) * 16 + rg + 8] = a3;
}

// ===================== 256x256 8-phase GEMM (T2+T3+T4+T5 template) ===================
#define BAR() do { __builtin_amdgcn_sched_barrier(0); __builtin_amdgcn_s_barrier(); \
                   __builtin_amdgcn_sched_barrier(0); } while (0)
#define VMCNT4() asm volatile("s_waitcnt vmcnt(4)" ::: "memory")
#define VMCNT0() asm volatile("s_waitcnt vmcnt(0)" ::: "memory")

#define STAGE(buf, tens, s, t) \
  gload16(((tens) ? Bw : A) + ((tens) ? offB[s] : offA[s]) + (t) * 64, \
          &lds.g[(buf) * 32768 + (tens) * 16384 + (s) * 4096 + tid * 8])

#define LDA(buf, h) do { \
  _Pragma("unroll") for (int i_ = 0; i_ < 4; i_++) { \
    const int r_ = ((h) * 128 + wm * 64 + i_ * 16 + fr) * 64; \
    a[i_][0] = *(const bf16x8*)&lds.g[(buf) * 32768 + r_ + ck0]; \
    a[i_][1] = *(const bf16x8*)&lds.g[(buf) * 32768 + r_ + ck1]; } } while (0)

#define LDB(buf, x, bb) do { \
  _Pragma("unroll") for (int j_ = 0; j_ < 2; j_++) { \
    const int r_ = ((x) * 128 + wn * 32 + j_ * 16 + fr) * 64; \
    bb[j_][0] = *(const bf16x8*)&lds.g[(buf) * 32768 + 16384 + r_ + ck0]; \
    bb[j_][1] = *(const bf16x8*)&lds.g[(buf) * 32768 + 16384 + r_ + ck1]; } } while (0)

#define DO_MFMA(h, x, bb) do { \
  __builtin_amdgcn_s_setprio(1); \
  _Pragma("unroll") for (int i_ = 0; i_ < 4; i_++) \
    _Pragma("unroll") for (int j_ = 0; j_ < 2; j_++) { \
      acc[(h) * 4 + i_][(x) * 2 + j_] = __builtin_amdgcn_mfma_f32_16x16x32_bf16( \
          a[i_][0], bb[j_][0], acc[(h) * 4 + i_][(x) * 2 + j_], 0, 0, 0); \
      acc[(h) * 4 + i_][(x) * 2 + j_] = __builtin_amdgcn_mfma_f32_16x16x32_bf16( \
          a[i_][1], bb[j_][1], acc[(h) * 4 + i_][(x) * 2 + j_], 0, 0, 0); } \
  __builtin_amdgcn_s_setprio(0); } while (0)

template<bool LORA, bool F32OUT>
__global__ __launch_bounds__(512, 2) void k_gemm(const u16* __restrict__ A,
                                                 const u16* __restrict__ Bw,
                                                 float* __restrict__ Cf,
                                                 u16* __restrict__ Cb,
                                                 const float* __restrict__ T,
                                                 const float* __restrict__ WB) {
  constexpr int K = 4096, N = 4096;
  __shared__ union {
    u16 g[2 * 2 * 16384];                       // 128 KB: [buf][A/B][16384 u16]
    struct { float t[256][20]; float w[256][20]; } ep;   // LoRA epilogue (40 KB)
  } lds;
  const int tid = threadIdx.x;
  const int lane = tid & 63, wid = tid >> 6;
  const int fr = lane & 15, fq = lane >> 4;
  const int wm = wid >> 2, wn = wid & 3;
  const int swz = (blockIdx.x & 7) * 32 + (blockIdx.x >> 3);   // XCD swizzle (256%8==0)
  const int m0 = (swz >> 4) << 8;
  const int n0 = (swz & 15) << 8;

  const int u = tid >> 3;
  const int cg = (tid & 7) ^ (u & 7);
  u32 offA[4], offB[4];
  offA[0] = (u32)(m0 + u) * K + cg * 8;
  offA[1] = (u32)(m0 + u + 128) * K + cg * 8;
  offA[2] = (u32)(m0 + u + 64) * K + cg * 8;
  offA[3] = (u32)(m0 + u + 192) * K + cg * 8;
  const int ub = (u & 31), uh = (u >> 5);
  offB[0] = (u32)(n0 + ub + uh * 64) * K + cg * 8;
  offB[1] = (u32)(n0 + ub + 128 + uh * 64) * K + cg * 8;
  offB[2] = (u32)(n0 + ub + uh * 64 + 32) * K + cg * 8;
  offB[3] = (u32)(n0 + ub + 128 + uh * 64 + 32) * K + cg * 8;

  const int ck0 = ((((fr >> 2) & 1) << 2) | (fq ^ (fr & 3))) * 8;
  const int ck1 = (((1 ^ ((fr >> 2) & 1)) << 2) | (fq ^ (fr & 3))) * 8;

  f32x4 acc[8][4];
  #pragma unroll
  for (int i = 0; i < 8; i++)
    #pragma unroll
    for (int j = 0; j < 4; j++) acc[i][j] = (f32x4){0.f, 0.f, 0.f, 0.f};
  bf16x8 a[4][2], b0[2][2], b1[2][2];

  STAGE(0, 0, 0, 0); STAGE(0, 0, 1, 0); STAGE(0, 1, 0, 0); STAGE(0, 1, 1, 0);
  STAGE(0, 0, 2, 0); STAGE(0, 0, 3, 0); STAGE(0, 1, 2, 0); STAGE(0, 1, 3, 0);
  STAGE(1, 0, 0, 1); STAGE(1, 0, 1, 1); STAGE(1, 1, 0, 1); STAGE(1, 1, 1, 1);
  VMCNT4();
  BAR();

  for (int it = 0; it < 32; ++it) {
    const int t1 = (2 * it + 1) & 63, t2 = (2 * it + 2) & 63, t3 = (2 * it + 3) & 63;
    LDA(0, 0); LDB(0, 0, b0);
    STAGE(1, 0, 2, t1); STAGE(1, 0, 3, t1);
    BAR(); DO_MFMA(0, 0, b0); BAR();
    LDB(0, 1, b1);
    STAGE(1, 1, 2, t1); STAGE(1, 1, 3, t1);
    BAR(); DO_MFMA(0, 1, b1); BAR();
    LDA(0, 1);
    STAGE(0, 0, 0, t2); STAGE(0, 0, 1, t2);
    BAR(); DO_MFMA(1, 0, b0); BAR();
    STAGE(0, 1, 0, t2); STAGE(0, 1, 1, t2);
    VMCNT4();
    BAR(); DO_MFMA(1, 1, b1); BAR();
    LDA(1, 0); LDB(1, 0, b0);
    STAGE(0, 0, 2, t2); STAGE(0, 0, 3, t2);
    BAR(); DO_MFMA(0, 0, b0); BAR();
    LDB(1, 1, b1);
    STAGE(0, 1, 2, t2); STAGE(0, 1, 3, t2);
    BAR(); DO_MFMA(0, 1, b1); BAR();
    LDA(1, 1);
    STAGE(1, 0, 0, t3); STAGE(1, 0, 1, t3);
    BAR(); DO_MFMA(1, 0, b0); BAR();
    STAGE(1, 1, 0, t3); STAGE(1, 1, 1, t3);
    VMCNT4();
    BAR(); DO_MFMA(1, 1, b1); BAR();
  }

  __syncthreads();
  if (LORA) {
    const int row = tid >> 1, hf = (tid & 1) * 8;
    *(float4*)&lds.ep.t[row][hf]     = *(const float4*)&T[(m0 + row) * 16 + hf];
    *(float4*)&lds.ep.t[row][hf + 4] = *(const float4*)&T[(m0 + row) * 16 + hf + 4];
    *(float4*)&lds.ep.w[row][hf]     = *(const float4*)&WB[(n0 + row) * 16 + hf];
    *(float4*)&lds.ep.w[row][hf + 4] = *(const float4*)&WB[(n0 + row) * 16 + hf + 4];
    __syncthreads();
  }

  float wc[4][16];
  if (LORA) {
    #pragma unroll
    for (int q = 0; q < 4; q++) {
      const int coll = wn * 64 + (q >> 1) * 32 + (q & 1) * 16 + fr;
      #pragma unroll
      for (int r4 = 0; r4 < 4; r4++)
        *(float4*)&wc[q][r4 * 4] = *(float4*)&lds.ep.w[coll][r4 * 4];
    }
  }
  #pragma unroll
  for (int h = 0; h < 2; h++)
    #pragma unroll
    for (int i = 0; i < 4; i++)
      #pragma unroll
      for (int jj = 0; jj < 4; jj++) {
        const int rowl = wm * 128 + h * 64 + i * 16 + fq * 4 + jj;
        float tr[16];
        if (LORA) {
          #pragma unroll
          for (int r4 = 0; r4 < 4; r4++)
            *(float4*)&tr[r4 * 4] = *(float4*)&lds.ep.t[rowl][r4 * 4];
        }
        #pragma unroll
        for (int q = 0; q < 4; q++) {
          float v = acc[h * 4 + i][q][jj];
          if (LORA) {
            float d = 0.f;
            #pragma unroll
            for (int r = 0; r < 16; r++) d += tr[r] * wc[q][r];
            v += 2.0f * d;
          }
          const int col = n0 + wn * 64 + (q >> 1) * 32 + (q & 1) * 16 + fr;
          if (F32OUT) Cf[(size_t)(m0 + rowl) * N + col] = v;
          else        Cb[(size_t)(m0 + rowl) * N + col] = f2b(v);
        }
      }
}

// ---------------- RoPE both tensors: (b,s,h,d)bf16 -> (b,h,s,d)bf16 ------------------
__global__ __launch_bounds__(256) void k_rope2(const u16* __restrict__ qin,
                                               const u16* __restrict__ kin,
                                               u16* __restrict__ qout,
                                               u16* __restrict__ kout,
                                               const float* __restrict__ fc,
                                               const float* __restrict__ fs) {
  const int sel = blockIdx.x >> 14;
  const u16* in  = sel ? kin  : qin;
  u16*       out = sel ? kout : qout;
  const float scale = sel ? 1.0f : 0.08838834764831845f;
  const int tid = (blockIdx.x & 16383) * 256 + threadIdx.x;   // B*H*S*32 threads
  const int c4 = tid & 31;
  const int s  = (tid >> 5) & 1023;
  const int h  = (tid >> 15) & 31;
  const int b  = tid >> 20;
  const ushort4 v = *(const ushort4*)&in[(((size_t)(b * 1024 + s) * 32 + h) * 128) + c4 * 4];
  const float2 c = *(const float2*)&fc[s * 64 + c4 * 2];
  const float2 sn = *(const float2*)&fs[s * 64 + c4 * 2];
  float vx = b2f(v.x), vy = b2f(v.y), vz = b2f(v.z), vw = b2f(v.w);
  float o0 = (vx * c.x - vy * sn.x) * scale;
  float o1 = (vx * sn.x + vy * c.x) * scale;
  float o2 = (vz * c.y - vw * sn.y) * scale;
  float o3 = (vz * sn.y + vw * c.y) * scale;
  uint2 o;
  o.x = (u32)f2b(o0) | ((u32)f2b(o1) << 16);
  o.y = (u32)f2b(o2) | ((u32)f2b(o3) << 16);
  *(uint2*)&out[(((size_t)(b * 32 + h) * 1024 + s) * 128) + c4 * 4] = o;
}

// ---- fused: V transpose (b,s,h,d)->(b,h,d,s) [blocks 0..16383]  +  wo fp32->bf16 ----
__global__ __launch_bounds__(256) void k_vt_cvt(const u16* __restrict__ Vb,
                                                u16* __restrict__ vt,
                                                const float* __restrict__ wo,
                                                u16* __restrict__ wo_bf) {
  __shared__ u16 tile[32][36];
  const int bid = blockIdx.x;
  const int t = threadIdx.x;
  if (bid < 16384) {
    const int dt = bid & 3;
    const int st = (bid >> 2) & 31;
    const int bh = bid >> 7;
    const int r = t >> 3, c4 = (t & 7) * 4;
    const ushort4 v = *(const ushort4*)
        &Vb[((size_t)((bh >> 5) * 1024 + st * 32 + r) * 32 + (bh & 31)) * 128 + dt * 32 + c4];
    tile[r][c4] = v.x; tile[r][c4 + 1] = v.y; tile[r][c4 + 2] = v.z; tile[r][c4 + 3] = v.w;
    __syncthreads();
    uint2 o;
    o.x = (u32)tile[c4][r]     | ((u32)tile[c4 + 1][r] << 16);
    o.y = (u32)tile[c4 + 2][r] | ((u32)tile[c4 + 3][r] << 16);
    *(uint2*)&vt[((size_t)bh * 128 + dt * 32 + r) * 1024 + st * 32 + c4] = o;
  } else {
    size_t i = (size_t)(bid - 16384) * 256 + t;
    const float4* s = (const float4*)wo + i * 2;
    float4 a = s[0], b = s[1];
    uint4 o;
    o.x = (u32)f2b(a.x) | ((u32)f2b(a.y) << 16);
    o.y = (u32)f2b(a.z) | ((u32)f2b(a.w) << 16);
    o.z = (u32)f2b(b.x) | ((u32)f2b(b.y) << 16);
    o.w = (u32)f2b(b.z) | ((u32)f2b(b.w) << 16);
    ((uint4*)wo_bf)[i] = o;
  }
}

// ========= flash attention v2: 4 waves x 16 q-rows, LDS K/V double-buffer ===========
// 2048 blocks of 256 thr: bid -> xcd=bid&7, qb=(bid>>3)&15, bh=(bid>>7)*8+xcd.
// All 16 q-blocks of a bh land on one XCD consecutively -> K/V (512KB) L2-resident.
// Per 32-k tile: K [32][128] (chunk ^= row&7) + V^T [128][32] (chunk ^= (row>>1)&3)
// staged via global_load_lds (linear dest + pre-swizzled source), counted vmcnt(4),
// raw s_barrier. P per wave padded to 40 elems/row (conflict-free).
__global__ __launch_bounds__(256) void k_attn(const u16* __restrict__ qb_,
                                              const u16* __restrict__ kb,
                                              const u16* __restrict__ vt,
                                              u16* __restrict__ ob) {
  __shared__ __align__(16) u16 KT[2][4096];
  __shared__ __align__(16) u16 VT[2][4096];
  __shared__ __align__(16) u16 PT[4][16 * 40];
  const int bid = blockIdx.x;
  const int xcd = bid & 7, qblk = (bid >> 3) & 15;
  const int bh = (bid >> 7) * 8 + xcd;
  const int q0b = qblk * 64;
  const int tid = threadIdx.x;
  const int w = tid >> 6, l = tid & 63;
  const int c = l & 15, g = l >> 4;
  const int q0 = q0b + w * 16;
  const u16* qbase = qb_ + (size_t)bh * (S_ * HD_);
  const u16* kbase = kb + (size_t)bh * (S_ * HD_);
  const u16* vbase = vt + (size_t)bh * (HD_ * S_);

  bf16x8 qf[4];
  #pragma unroll
  for (int ks = 0; ks < 4; ks++)
    qf[ks] = *(const bf16x8*)&qbase[(q0 + c) * 128 + ks * 32 + g * 8];
  f32x4 accO[8];
  #pragma unroll
  for (int d = 0; d < 8; d++) accO[d] = (f32x4){0.f, 0.f, 0.f, 0.f};
  float mrun[4] = {-1e30f, -1e30f, -1e30f, -1e30f};
  float lrun[4] = {0.f, 0.f, 0.f, 0.f};

  const int nkb_w = (q0 + 47) >> 5;        // this wave's k-tiles
  const int nkbB  = (q0b + 95) >> 5;       // block max (= wave 3's)

  // staging: 4 gload16 per thread per tile (K 2 passes + V 2 passes), linear LDS dest
#define STG_KV(buf, kt) do { \
    const int r_ = tid >> 4, cs_ = ((tid & 15) ^ (r_ & 7)) * 8; \
    gload16(kbase + (size_t)((kt) * 32 + r_) * 128 + cs_,      &KT[buf][tid * 8]); \
    gload16(kbase + (size_t)((kt) * 32 + 16 + r_) * 128 + cs_, &KT[buf][2048 + tid * 8]); \
    const int u_ = tid >> 2, cv_ = ((tid & 3) ^ ((u_ >> 1) & 3)) * 8; \
    gload16(vbase + (size_t)u_ * 1024 + (kt) * 32 + cv_,        &VT[buf][tid * 8]); \
    gload16(vbase + (size_t)(u_ + 64) * 1024 + (kt) * 32 + cv_, &VT[buf][2048 + tid * 8]); \
  } while (0)

  STG_KV(0, 0);
  for (int kbi = 0; kbi < nkbB; kbi++) {
    const int cur = kbi & 1;
    if (kbi + 1 < nkbB) {
      STG_KV(cur ^ 1, kbi + 1);
      VMCNT4();
    } else {
      VMCNT0();
    }
    BAR();
    if (kbi < nkb_w) {
      const int k0 = kbi * 32;
      f32x4 s0 = (f32x4){0.f, 0.f, 0.f, 0.f}, s1 = (f32x4){0.f, 0.f, 0.f, 0.f};
      #pragma unroll
      for (int ks = 0; ks < 4; ks++) {
        const int ch = ((ks * 4 + g) ^ (c & 7)) * 8;
        bf16x8 kb0 = *(const bf16x8*)&KT[cur][c * 128 + ch];
        bf16x8 kb1 = *(const bf16x8*)&KT[cur][(16 + c) * 128 + ch];
        s0 = __builtin_amdgcn_mfma_f32_16x16x32_bf16(qf[ks], kb0, s0, 0, 0, 0);
        s1 = __builtin_amdgcn_mfma_f32_16x16x32_bf16(qf[ks], kb1, s1, 0, 0, 0);
      }
      if (kbi == nkb_w - 1) {
        #pragma unroll
        for (int j = 0; j < 4; j++) {
          int q = q0 + g * 4 + j;
          if (k0 + c > q)      s0[j] = -1e9f;
          if (k0 + 16 + c > q) s1[j] = -1e9f;
        }
      }
      float pv0[4], pv1[4], corr[4];
      #pragma unroll
      for (int j = 0; j < 4; j++) {
        float mx = fmaxf(s0[j], s1[j]);
        #pragma unroll
        for (int off = 8; off; off >>= 1) mx = fmaxf(mx, __shfl_xor(mx, off, 16));
        float mn = fmaxf(mrun[j], mx);
        corr[j] = __expf(mrun[j] - mn);
        mrun[j] = mn;
        float p0 = __expf(s0[j] - mn);
        float p1 = __expf(s1[j] - mn);
        float rs = p0 + p1;
        #pragma unroll
        for (int off = 8; off; off >>= 1) rs += __shfl_xor(rs, off, 16);
        lrun[j] = lrun[j] * corr[j] + rs;
        pv0[j] = p0; pv1[j] = p1;
      }
      #pragma unroll
      for (int j = 0; j < 4; j++) {
        PT[w][(g * 4 + j) * 40 + c]      = f2b(pv0[j]);
        PT[w][(g * 4 + j) * 40 + 16 + c] = f2b(pv1[j]);
      }
      asm volatile("s_waitcnt lgkmcnt(0)" ::: "memory");
      __builtin_amdgcn_sched_barrier(0);
      bf16x8 pa = *(const bf16x8*)&PT[w][c * 40 + g * 8];
      #pragma unroll
      for (int d = 0; d < 8; d++) {
        #pragma unroll
        for (int j = 0; j < 4; j++) accO[d][j] *= corr[j];
      }
      #pragma unroll
      for (int d = 0; d < 8; d++) {
        const int u = d * 16 + c;
        bf16x8 vf = *(const bf16x8*)&VT[cur][u * 32 + ((g ^ ((c >> 1) & 3)) * 8)];
        accO[d] = __builtin_amdgcn_mfma_f32_16x16x32_bf16(pa, vf, accO[d], 0, 0, 0);
      }
    }
    BAR();
  }
#undef STG_KV

  float inv[4];
  #pragma unroll
  for (int j = 0; j < 4; j++) inv[j] = 1.0f / lrun[j];
  #pragma unroll
  for (int d = 0; d < 8; d++) {
    #pragma unroll
    for (int j = 0; j < 4; j++) {
      float val = accO[d][j] * inv[j];
      ob[(size_t)((bh >> 5) * 1024 + q0 + g * 4 + j) * 4096 + (bh & 31) * 128 + d * 16 + c]
          = f2b(val);
    }
  }
}

// =====================================================================================
extern "C" void kernel_launch(void* const* d_in, const int* in_sizes, int n_in,
                              void* d_out, int out_size, void* d_ws, size_t ws_size,
                              hipStream_t stream) {
  const float* x    = (const float*)d_in[0];
  const float* wq_w = (const float*)d_in[1];
  const float* wq_a = (const float*)d_in[2];
  const float* wq_b = (const float*)d_in[3];
  const float* wk_w = (const float*)d_in[4];
  const float* wv_w = (const float*)d_in[5];
  const float* wv_a = (const float*)d_in[6];
  const float* wv_b = (const float*)d_in[7];
  const float* wo_w = (const float*)d_in[8];
  const float* fc   = (const float*)d_in[9];
  const float* fs   = (const float*)d_in[10];
  // d_in[11] = mask (causal, applied analytically), d_in[12] = start_pos (0)

  char* p = (char*)d_ws;
  const size_t SZ_BF = (size_t)M_ * D_ * 2;   // 32 MB
  u16* s0 = (u16*)(p + 0 * SZ_BF);   // x_bf   -> wo_bf
  u16* s1 = (u16*)(p + 1 * SZ_BF);   // wq_bf  -> att_bf
  u16* s2 = (u16*)(p + 2 * SZ_BF);   // wk_bf  -> q_bf
  u16* s3 = (u16*)(p + 3 * SZ_BF);   // wv_bf  -> k_bf
  u16* s4 = (u16*)(p + 4 * SZ_BF);   // Qb     -> v_t
  u16* s5 = (u16*)(p + 5 * SZ_BF);   // Kb
  u16* s6 = (u16*)(p + 6 * SZ_BF);   // Vb
  float* t_q = (float*)(p + 7 * SZ_BF);
  float* t_v = t_q + (size_t)M_ * 16;

  // 1. bf16 conversions (x, wq, wk, wv) in one dispatch
  k_cvt4<<<32768, 256, 0, stream>>>(x, wq_w, wk_w, wv_w, s0, s1, s2, s3);

  // 2. LoRA intermediates (fp32 exact, from fp32 x)
  k_lora_t<<<128, 256, 0, stream>>>(x, wq_a, wv_a, t_q, t_v);

  // 3. projections (256x256 8-phase bf16 MFMA; LoRA rank-16 fp32 epilogue for Q and V)
  k_gemm<true,  false><<<256, 512, 0, stream>>>(s0, s1, nullptr, s4, t_q, wq_b);        // Qb
  k_gemm<false, false><<<256, 512, 0, stream>>>(s0, s2, nullptr, s5, nullptr, nullptr); // Kb
  k_gemm<true,  false><<<256, 512, 0, stream>>>(s0, s3, nullptr, s6, t_v, wv_b);        // Vb

  // 4. RoPE Q (+1/sqrt(HD)) and K -> (b,h,s,d) bf16, one dispatch
  k_rope2<<<32768, 256, 0, stream>>>(s4, s5, s2, s3, fc, fs);  // Qb->q_bf(s2), Kb->k_bf(s3)

  // 5. V -> (b,h,d,s) bf16 (into s4; Qb dead)  +  wo convert (into s0; x_bf dead)
  k_vt_cvt<<<24576, 256, 0, stream>>>(s6, s4, wo_w, s0);

  // 6. causal flash attention v2 -> (b,s,h*d) bf16 (wq_bf slot s1 dead)
  k_attn<<<2048, 256, 0, stream>>>(s2, s3, s4, s1);

  // 7. output projection -> fp32 d_out
  k_gemm<false, true><<<256, 512, 0, stream>>>(s1, s0, (float*)d_out, nullptr, nullptr, nullptr);
}

// Round 8
// 1162.168 us; speedup vs baseline: 2.9905x; 1.5947x over previous
//
#include <hip/hip_runtime.h>

typedef unsigned short u16;
typedef unsigned int   u32;

typedef __bf16 bf16x8 __attribute__((ext_vector_type(8)));
typedef float  f32x4  __attribute__((ext_vector_type(4)));

typedef __attribute__((address_space(1))) const u32* gas_u32;
typedef __attribute__((address_space(3))) u32*       las_u32;

#define B_  4
#define S_  1024
#define D_  4096
#define H_  32
#define HD_ 128
#define M_  4096

__device__ __forceinline__ void gload16(const void* g, void* l) {
  __builtin_amdgcn_global_load_lds((gas_u32)g, (las_u32)l, 16, 0, 0);
}

__device__ __forceinline__ u16 f2b(float x) {
  u32 u = __float_as_uint(x);
  u32 r = (u + 0x7fffu + ((u >> 16) & 1u)) >> 16;
  return (u16)r;
}
__device__ __forceinline__ float b2f(u16 x) {
  return __uint_as_float((u32)x << 16);
}

// ---------------- fp32 -> bf16 convert: 4 tensors in one dispatch ----------------
__global__ __launch_bounds__(256) void k_cvt4(const float* __restrict__ sa,
                                              const float* __restrict__ sb,
                                              const float* __restrict__ sc,
                                              const float* __restrict__ sd,
                                              u16* __restrict__ da,
                                              u16* __restrict__ db,
                                              u16* __restrict__ dc,
                                              u16* __restrict__ dd) {
  const int sel = blockIdx.x >> 13;          // 4 x 8192 blocks
  const float* src = sel == 0 ? sa : sel == 1 ? sb : sel == 2 ? sc : sd;
  u16*         dst = sel == 0 ? da : sel == 1 ? db : sel == 2 ? dc : dd;
  size_t i = (size_t)(blockIdx.x & 8191) * 256 + threadIdx.x;
  const float4* s = (const float4*)src + i * 2;
  float4 a = s[0], b = s[1];
  uint4 o;
  o.x = (u32)f2b(a.x) | ((u32)f2b(a.y) << 16);
  o.y = (u32)f2b(a.z) | ((u32)f2b(a.w) << 16);
  o.z = (u32)f2b(b.x) | ((u32)f2b(b.y) << 16);
  o.w = (u32)f2b(b.z) | ((u32)f2b(b.w) << 16);
  ((uint4*)dst)[i] = o;
}

// ---------------- LoRA intermediates: t_q = x@wq_a^T, t_v = x@wv_a^T (fp32 exact) ----
__global__ __launch_bounds__(256) void k_lora_t(const float* __restrict__ x,
                                                const float* __restrict__ wqa,
                                                const float* __restrict__ wva,
                                                float* __restrict__ tq,
                                                float* __restrict__ tv) {
  __shared__ float xs[32][136];
  __shared__ float was[32][136];
  const int tid = threadIdx.x;
  const int m0 = blockIdx.x * 32;
  const int mr = tid >> 3, rg = tid & 7;
  float a0 = 0.f, a1 = 0.f, a2 = 0.f, a3 = 0.f;
  for (int kc = 0; kc < 4096; kc += 128) {
    #pragma unroll
    for (int i = 0; i < 4; i++) {
      int e = (tid + 256 * i) * 4;
      int row = e >> 7, col = e & 127;
      *(float4*)&xs[row][col] = *(const float4*)&x[(size_t)(m0 + row) * 4096 + kc + col];
      const float* wsrc = (row < 16) ? &wqa[row * 4096 + kc + col]
                                     : &wva[(row - 16) * 4096 + kc + col];
      *(float4*)&was[row][col] = *(const float4*)wsrc;
    }
    __syncthreads();
    #pragma unroll 8
    for (int ks = 0; ks < 32; ks++) {
      float4 xv = *(float4*)&xs[mr][ks * 4];
      float4 w0 = *(float4*)&was[rg][ks * 4];
      float4 w1 = *(float4*)&was[rg + 8][ks * 4];
      float4 w2 = *(float4*)&was[rg + 16][ks * 4];
      float4 w3 = *(float4*)&was[rg + 24][ks * 4];
      a0 += xv.x * w0.x + xv.y * w0.y + xv.z * w0.z + xv.w * w0.w;
      a1 += xv.x * w1.x + xv.y * w1.y + xv.z * w1.z + xv.w * w1.w;
      a2 += xv.x * w2.x + xv.y * w2.y + xv.z * w2.z + xv.w * w2.w;
      a3 += xv.x * w3.x + xv.y * w3.y + xv.z * w3.z + xv.w * w3.w;
    }
    __syncthreads();
  }
  tq[(m0 + mr) * 16 + rg]     = a0;
  tq[(m0 + mr) * 16 + rg + 8] = a1;
  tv[(m0 + mr) * 16 + rg]     = a2;
  tv[(m0 + mr) * 16 + rg + 8] = a3;
}

// ===================== 256x256 8-phase GEMM (T2+T3+T4+T5 template) ===================
// LDS swizzle = m201's HW-verified st_16x32: byte ^= ((byte>>9)&1)<<5, i.e. 16B-chunk
// index ^= ((row>>2)&1)<<1, applied BOTH sides (pre-swizzled global source chunk on
// staging + swizzled ds_read chunk). row bit2 == fr bit2 on all fragment reads.
#define BAR() do { __builtin_amdgcn_sched_barrier(0); __builtin_amdgcn_s_barrier(); \
                   __builtin_amdgcn_sched_barrier(0); } while (0)
#define VMCNT4() asm volatile("s_waitcnt vmcnt(4)" ::: "memory")
#define VMCNT0() asm volatile("s_waitcnt vmcnt(0)" ::: "memory")

#define STAGE(buf, tens, s, t) \
  gload16(((tens) ? Bw : A) + ((tens) ? offB[s] : offA[s]) + (t) * 64, \
          &lds.g[(buf) * 32768 + (tens) * 16384 + (s) * 4096 + tid * 8])

#define LDA(buf, h) do { \
  _Pragma("unroll") for (int i_ = 0; i_ < 4; i_++) { \
    const int r_ = ((h) * 128 + wm * 64 + i_ * 16 + fr) * 64; \
    a[i_][0] = *(const bf16x8*)&lds.g[(buf) * 32768 + r_ + ck0]; \
    a[i_][1] = *(const bf16x8*)&lds.g[(buf) * 32768 + r_ + ck0 + 32]; } } while (0)

#define LDB(buf, x, bb) do { \
  _Pragma("unroll") for (int j_ = 0; j_ < 2; j_++) { \
    const int r_ = ((x) * 128 + wn * 32 + j_ * 16 + fr) * 64; \
    bb[j_][0] = *(const bf16x8*)&lds.g[(buf) * 32768 + 16384 + r_ + ck0]; \
    bb[j_][1] = *(const bf16x8*)&lds.g[(buf) * 32768 + 16384 + r_ + ck0 + 32]; } } while (0)

#define DO_MFMA(h, x, bb) do { \
  __builtin_amdgcn_s_setprio(1); \
  _Pragma("unroll") for (int i_ = 0; i_ < 4; i_++) \
    _Pragma("unroll") for (int j_ = 0; j_ < 2; j_++) { \
      acc[(h) * 4 + i_][(x) * 2 + j_] = __builtin_amdgcn_mfma_f32_16x16x32_bf16( \
          a[i_][0], bb[j_][0], acc[(h) * 4 + i_][(x) * 2 + j_], 0, 0, 0); \
      acc[(h) * 4 + i_][(x) * 2 + j_] = __builtin_amdgcn_mfma_f32_16x16x32_bf16( \
          a[i_][1], bb[j_][1], acc[(h) * 4 + i_][(x) * 2 + j_], 0, 0, 0); } \
  __builtin_amdgcn_s_setprio(0); } while (0)

template<bool LORA, bool F32OUT>
__global__ __launch_bounds__(512, 2) void k_gemm(const u16* __restrict__ A,
                                                 const u16* __restrict__ Bw,
                                                 float* __restrict__ Cf,
                                                 u16* __restrict__ Cb,
                                                 const float* __restrict__ T,
                                                 const float* __restrict__ WB) {
  constexpr int K = 4096, N = 4096;
  __shared__ __align__(16) union {
    u16 g[2 * 2 * 16384];                       // 128 KB: [buf][A/B][16384 u16]
    struct { float t[256][20]; float w[256][20]; } ep;   // LoRA epilogue (40 KB)
  } lds;
  const int tid = threadIdx.x;
  const int lane = tid & 63, wid = tid >> 6;
  const int fr = lane & 15, fq = lane >> 4;
  const int wm = wid >> 2, wn = wid & 3;
  const int swz = (blockIdx.x & 7) * 32 + (blockIdx.x >> 3);   // XCD swizzle (256%8==0)
  const int m0 = (swz >> 4) << 8;
  const int n0 = (swz & 15) << 8;

  // staging: thread -> (segment row u = tid>>3, LDS chunk tid&7); st_16x32 swizzle:
  // global chunk = ldschunk ^ ((row>>2)&1)<<1, row = s*64 + u -> bit2 = (tid>>5)&1
  const int u = tid >> 3;
  const int cg = (tid & 7) ^ (((tid >> 5) & 1) << 1);
  u32 offA[4], offB[4];
  offA[0] = (u32)(m0 + u) * K + cg * 8;
  offA[1] = (u32)(m0 + u + 128) * K + cg * 8;
  offA[2] = (u32)(m0 + u + 64) * K + cg * 8;
  offA[3] = (u32)(m0 + u + 192) * K + cg * 8;
  const int ub = (u & 31), uh = (u >> 5);
  offB[0] = (u32)(n0 + ub + uh * 64) * K + cg * 8;
  offB[1] = (u32)(n0 + ub + 128 + uh * 64) * K + cg * 8;
  offB[2] = (u32)(n0 + ub + uh * 64 + 32) * K + cg * 8;
  offB[3] = (u32)(n0 + ub + 128 + uh * 64 + 32) * K + cg * 8;

  // ds_read chunk for kk=0 (global chunk fq): ck0 = (fq ^ ((fr>>2)&1)<<1)*8; kk=1: +32
  const int ck0 = (fq ^ (((fr >> 2) & 1) << 1)) * 8;

  f32x4 acc[8][4];
  #pragma unroll
  for (int i = 0; i < 8; i++)
    #pragma unroll
    for (int j = 0; j < 4; j++) acc[i][j] = (f32x4){0.f, 0.f, 0.f, 0.f};
  bf16x8 a[4][2], b0[2][2], b1[2][2];

  STAGE(0, 0, 0, 0); STAGE(0, 0, 1, 0); STAGE(0, 1, 0, 0); STAGE(0, 1, 1, 0);
  STAGE(0, 0, 2, 0); STAGE(0, 0, 3, 0); STAGE(0, 1, 2, 0); STAGE(0, 1, 3, 0);
  STAGE(1, 0, 0, 1); STAGE(1, 0, 1, 1); STAGE(1, 1, 0, 1); STAGE(1, 1, 1, 1);
  VMCNT4();
  BAR();

  for (int it = 0; it < 32; ++it) {
    const int t1 = (2 * it + 1) & 63, t2 = (2 * it + 2) & 63, t3 = (2 * it + 3) & 63;
    LDA(0, 0); LDB(0, 0, b0);
    STAGE(1, 0, 2, t1); STAGE(1, 0, 3, t1);
    BAR(); DO_MFMA(0, 0, b0); BAR();
    LDB(0, 1, b1);
    STAGE(1, 1, 2, t1); STAGE(1, 1, 3, t1);
    BAR(); DO_MFMA(0, 1, b1); BAR();
    LDA(0, 1);
    STAGE(0, 0, 0, t2); STAGE(0, 0, 1, t2);
    BAR(); DO_MFMA(1, 0, b0); BAR();
    STAGE(0, 1, 0, t2); STAGE(0, 1, 1, t2);
    VMCNT4();
    BAR(); DO_MFMA(1, 1, b1); BAR();
    LDA(1, 0); LDB(1, 0, b0);
    STAGE(0, 0, 2, t2); STAGE(0, 0, 3, t2);
    BAR(); DO_MFMA(0, 0, b0); BAR();
    LDB(1, 1, b1);
    STAGE(0, 1, 2, t2); STAGE(0, 1, 3, t2);
    BAR(); DO_MFMA(0, 1, b1); BAR();
    LDA(1, 1);
    STAGE(1, 0, 0, t3); STAGE(1, 0, 1, t3);
    BAR(); DO_MFMA(1, 0, b0); BAR();
    STAGE(1, 1, 0, t3); STAGE(1, 1, 1, t3);
    VMCNT4();
    BAR(); DO_MFMA(1, 1, b1); BAR();
  }

  __syncthreads();
  if (LORA) {
    const int row = tid >> 1, hf = (tid & 1) * 8;
    *(float4*)&lds.ep.t[row][hf]     = *(const float4*)&T[(m0 + row) * 16 + hf];
    *(float4*)&lds.ep.t[row][hf + 4] = *(const float4*)&T[(m0 + row) * 16 + hf + 4];
    *(float4*)&lds.ep.w[row][hf]     = *(const float4*)&WB[(n0 + row) * 16 + hf];
    *(float4*)&lds.ep.w[row][hf + 4] = *(const float4*)&WB[(n0 + row) * 16 + hf + 4];
    __syncthreads();
  }

  float wc[4][16];
  if (LORA) {
    #pragma unroll
    for (int q = 0; q < 4; q++) {
      const int coll = wn * 64 + (q >> 1) * 32 + (q & 1) * 16 + fr;
      #pragma unroll
      for (int r4 = 0; r4 < 4; r4++)
        *(float4*)&wc[q][r4 * 4] = *(float4*)&lds.ep.w[coll][r4 * 4];
    }
  }
  #pragma unroll
  for (int h = 0; h < 2; h++)
    #pragma unroll
    for (int i = 0; i < 4; i++)
      #pragma unroll
      for (int jj = 0; jj < 4; jj++) {
        const int rowl = wm * 128 + h * 64 + i * 16 + fq * 4 + jj;
        float tr[16];
        if (LORA) {
          #pragma unroll
          for (int r4 = 0; r4 < 4; r4++)
            *(float4*)&tr[r4 * 4] = *(float4*)&lds.ep.t[rowl][r4 * 4];
        }
        #pragma unroll
        for (int q = 0; q < 4; q++) {
          float v = acc[h * 4 + i][q][jj];
          if (LORA) {
            float d = 0.f;
            #pragma unroll
            for (int r = 0; r < 16; r++) d += tr[r] * wc[q][r];
            v += 2.0f * d;
          }
          const int col = n0 + wn * 64 + (q >> 1) * 32 + (q & 1) * 16 + fr;
          if (F32OUT) Cf[(size_t)(m0 + rowl) * N + col] = v;
          else        Cb[(size_t)(m0 + rowl) * N + col] = f2b(v);
        }
      }
}

// ---------------- RoPE both tensors: (b,s,h,d)bf16 -> (b,h,s,d)bf16 ------------------
__global__ __launch_bounds__(256) void k_rope2(const u16* __restrict__ qin,
                                               const u16* __restrict__ kin,
                                               u16* __restrict__ qout,
                                               u16* __restrict__ kout,
                                               const float* __restrict__ fc,
                                               const float* __restrict__ fs) {
  const int sel = blockIdx.x >> 14;
  const u16* in  = sel ? kin  : qin;
  u16*       out = sel ? kout : qout;
  const float scale = sel ? 1.0f : 0.08838834764831845f;
  const int tid = (blockIdx.x & 16383) * 256 + threadIdx.x;   // B*H*S*32 threads
  const int c4 = tid & 31;
  const int s  = (tid >> 5) & 1023;
  const int h  = (tid >> 15) & 31;
  const int b  = tid >> 20;
  const ushort4 v = *(const ushort4*)&in[(((size_t)(b * 1024 + s) * 32 + h) * 128) + c4 * 4];
  const float2 c = *(const float2*)&fc[s * 64 + c4 * 2];
  const float2 sn = *(const float2*)&fs[s * 64 + c4 * 2];
  float vx = b2f(v.x), vy = b2f(v.y), vz = b2f(v.z), vw = b2f(v.w);
  float o0 = (vx * c.x - vy * sn.x) * scale;
  float o1 = (vx * sn.x + vy * c.x) * scale;
  float o2 = (vz * c.y - vw * sn.y) * scale;
  float o3 = (vz * sn.y + vw * c.y) * scale;
  uint2 o;
  o.x = (u32)f2b(o0) | ((u32)f2b(o1) << 16);
  o.y = (u32)f2b(o2) | ((u32)f2b(o3) << 16);
  *(uint2*)&out[(((size_t)(b * 32 + h) * 1024 + s) * 128) + c4 * 4] = o;
}

// ---- fused: V transpose (b,s,h,d)->(b,h,d,s) [blocks 0..16383]  +  wo fp32->bf16 ----
__global__ __launch_bounds__(256) void k_vt_cvt(const u16* __restrict__ Vb,
                                                u16* __restrict__ vt,
                                                const float* __restrict__ wo,
                                                u16* __restrict__ wo_bf) {
  __shared__ u16 tile[32][36];
  const int bid = blockIdx.x;
  const int t = threadIdx.x;
  if (bid < 16384) {
    const int dt = bid & 3;
    const int st = (bid >> 2) & 31;
    const int bh = bid >> 7;
    const int r = t >> 3, c4 = (t & 7) * 4;
    const ushort4 v = *(const ushort4*)
        &Vb[((size_t)((bh >> 5) * 1024 + st * 32 + r) * 32 + (bh & 31)) * 128 + dt * 32 + c4];
    tile[r][c4] = v.x; tile[r][c4 + 1] = v.y; tile[r][c4 + 2] = v.z; tile[r][c4 + 3] = v.w;
    __syncthreads();
    uint2 o;
    o.x = (u32)tile[c4][r]     | ((u32)tile[c4 + 1][r] << 16);
    o.y = (u32)tile[c4 + 2][r] | ((u32)tile[c4 + 3][r] << 16);
    *(uint2*)&vt[((size_t)bh * 128 + dt * 32 + r) * 1024 + st * 32 + c4] = o;
  } else {
    size_t i = (size_t)(bid - 16384) * 256 + t;
    const float4* s = (const float4*)wo + i * 2;
    float4 a = s[0], b = s[1];
    uint4 o;
    o.x = (u32)f2b(a.x) | ((u32)f2b(a.y) << 16);
    o.y = (u32)f2b(a.z) | ((u32)f2b(a.w) << 16);
    o.z = (u32)f2b(b.x) | ((u32)f2b(b.y) << 16);
    o.w = (u32)f2b(b.z) | ((u32)f2b(b.w) << 16);
    ((uint4*)wo_bf)[i] = o;
  }
}

// ========= flash attention v2: 4 waves x 16 q-rows, LDS K/V double-buffer ===========
__global__ __launch_bounds__(256) void k_attn(const u16* __restrict__ qb_,
                                              const u16* __restrict__ kb,
                                              const u16* __restrict__ vt,
                                              u16* __restrict__ ob) {
  __shared__ __align__(16) u16 KT[2][4096];
  __shared__ __align__(16) u16 VT[2][4096];
  __shared__ __align__(16) u16 PT[4][16 * 40];
  const int bid = blockIdx.x;
  const int xcd = bid & 7, qblk = (bid >> 3) & 15;
  const int bh = (bid >> 7) * 8 + xcd;
  const int q0b = qblk * 64;
  const int tid = threadIdx.x;
  const int w = tid >> 6, l = tid & 63;
  const int c = l & 15, g = l >> 4;
  const int q0 = q0b + w * 16;
  const u16* qbase = qb_ + (size_t)bh * (S_ * HD_);
  const u16* kbase = kb + (size_t)bh * (S_ * HD_);
  const u16* vbase = vt + (size_t)bh * (HD_ * S_);

  bf16x8 qf[4];
  #pragma unroll
  for (int ks = 0; ks < 4; ks++)
    qf[ks] = *(const bf16x8*)&qbase[(q0 + c) * 128 + ks * 32 + g * 8];
  f32x4 accO[8];
  #pragma unroll
  for (int d = 0; d < 8; d++) accO[d] = (f32x4){0.f, 0.f, 0.f, 0.f};
  float mrun[4] = {-1e30f, -1e30f, -1e30f, -1e30f};
  float lrun[4] = {0.f, 0.f, 0.f, 0.f};

  const int nkb_w = (q0 + 47) >> 5;        // this wave's k-tiles
  const int nkbB  = (q0b + 95) >> 5;       // block max (= wave 3's)

#define STG_KV(buf, kt) do { \
    const int r_ = tid >> 4, cs_ = ((tid & 15) ^ (r_ & 7)) * 8; \
    gload16(kbase + (size_t)((kt) * 32 + r_) * 128 + cs_,      &KT[buf][tid * 8]); \
    gload16(kbase + (size_t)((kt) * 32 + 16 + r_) * 128 + cs_, &KT[buf][2048 + tid * 8]); \
    const int u_ = tid >> 2, cv_ = ((tid & 3) ^ ((u_ >> 1) & 3)) * 8; \
    gload16(vbase + (size_t)u_ * 1024 + (kt) * 32 + cv_,        &VT[buf][tid * 8]); \
    gload16(vbase + (size_t)(u_ + 64) * 1024 + (kt) * 32 + cv_, &VT[buf][2048 + tid * 8]); \
  } while (0)

  STG_KV(0, 0);
  for (int kbi = 0; kbi < nkbB; kbi++) {
    const int cur = kbi & 1;
    if (kbi + 1 < nkbB) {
      STG_KV(cur ^ 1, kbi + 1);
      VMCNT4();
    } else {
      VMCNT0();
    }
    BAR();
    if (kbi < nkb_w) {
      const int k0 = kbi * 32;
      f32x4 s0 = (f32x4){0.f, 0.f, 0.f, 0.f}, s1 = (f32x4){0.f, 0.f, 0.f, 0.f};
      #pragma unroll
      for (int ks = 0; ks < 4; ks++) {
        const int ch = ((ks * 4 + g) ^ (c & 7)) * 8;
        bf16x8 kb0 = *(const bf16x8*)&KT[cur][c * 128 + ch];
        bf16x8 kb1 = *(const bf16x8*)&KT[cur][(16 + c) * 128 + ch];
        s0 = __builtin_amdgcn_mfma_f32_16x16x32_bf16(qf[ks], kb0, s0, 0, 0, 0);
        s1 = __builtin_amdgcn_mfma_f32_16x16x32_bf16(qf[ks], kb1, s1, 0, 0, 0);
      }
      if (kbi == nkb_w - 1) {
        #pragma unroll
        for (int j = 0; j < 4; j++) {
          int q = q0 + g * 4 + j;
          if (k0 + c > q)      s0[j] = -1e9f;
          if (k0 + 16 + c > q) s1[j] = -1e9f;
        }
      }
      float pv0[4], pv1[4], corr[4];
      #pragma unroll
      for (int j = 0; j < 4; j++) {
        float mx = fmaxf(s0[j], s1[j]);
        #pragma unroll
        for (int off = 8; off; off >>= 1) mx = fmaxf(mx, __shfl_xor(mx, off, 16));
        float mn = fmaxf(mrun[j], mx);
        corr[j] = __expf(mrun[j] - mn);
        mrun[j] = mn;
        float p0 = __expf(s0[j] - mn);
        float p1 = __expf(s1[j] - mn);
        float rs = p0 + p1;
        #pragma unroll
        for (int off = 8; off; off >>= 1) rs += __shfl_xor(rs, off, 16);
        lrun[j] = lrun[j] * corr[j] + rs;
        pv0[j] = p0; pv1[j] = p1;
      }
      #pragma unroll
      for (int j = 0; j < 4; j++) {
        PT[w][(g * 4 + j) * 40 + c]      = f2b(pv0[j]);
        PT[w][(g * 4 + j) * 40 + 16 + c] = f2b(pv1[j]);
      }
      asm volatile("s_waitcnt lgkmcnt(0)" ::: "memory");
      __builtin_amdgcn_sched_barrier(0);
      bf16x8 pa = *(const bf16x8*)&PT[w][c * 40 + g * 8];
      #pragma unroll
      for (int d = 0; d < 8; d++) {
        #pragma unroll
        for (int j = 0; j < 4; j++) accO[d][j] *= corr[j];
      }
      #pragma unroll
      for (int d = 0; d < 8; d++) {
        const int u2 = d * 16 + c;
        bf16x8 vf = *(const bf16x8*)&VT[cur][u2 * 32 + ((g ^ ((c >> 1) & 3)) * 8)];
        accO[d] = __builtin_amdgcn_mfma_f32_16x16x32_bf16(pa, vf, accO[d], 0, 0, 0);
      }
    }
    BAR();
  }
#undef STG_KV

  float inv[4];
  #pragma unroll
  for (int j = 0; j < 4; j++) inv[j] = 1.0f / lrun[j];
  #pragma unroll
  for (int d = 0; d < 8; d++) {
    #pragma unroll
    for (int j = 0; j < 4; j++) {
      float val = accO[d][j] * inv[j];
      ob[(size_t)((bh >> 5) * 1024 + q0 + g * 4 + j) * 4096 + (bh & 31) * 128 + d * 16 + c]
          = f2b(val);
    }
  }
}

// =====================================================================================
extern "C" void kernel_launch(void* const* d_in, const int* in_sizes, int n_in,
                              void* d_out, int out_size, void* d_ws, size_t ws_size,
                              hipStream_t stream) {
  const float* x    = (const float*)d_in[0];
  const float* wq_w = (const float*)d_in[1];
  const float* wq_a = (const float*)d_in[2];
  const float* wq_b = (const float*)d_in[3];
  const float* wk_w = (const float*)d_in[4];
  const float* wv_w = (const float*)d_in[5];
  const float* wv_a = (const float*)d_in[6];
  const float* wv_b = (const float*)d_in[7];
  const float* wo_w = (const float*)d_in[8];
  const float* fc   = (const float*)d_in[9];
  const float* fs   = (const float*)d_in[10];
  // d_in[11] = mask (causal, applied analytically), d_in[12] = start_pos (0)

  char* p = (char*)d_ws;
  const size_t SZ_BF = (size_t)M_ * D_ * 2;   // 32 MB
  u16* s0 = (u16*)(p + 0 * SZ_BF);   // x_bf   -> wo_bf
  u16* s1 = (u16*)(p + 1 * SZ_BF);   // wq_bf  -> att_bf
  u16* s2 = (u16*)(p + 2 * SZ_BF);   // wk_bf  -> q_bf
  u16* s3 = (u16*)(p + 3 * SZ_BF);   // wv_bf  -> k_bf
  u16* s4 = (u16*)(p + 4 * SZ_BF);   // Qb     -> v_t
  u16* s5 = (u16*)(p + 5 * SZ_BF);   // Kb
  u16* s6 = (u16*)(p + 6 * SZ_BF);   // Vb
  float* t_q = (float*)(p + 7 * SZ_BF);
  float* t_v = t_q + (size_t)M_ * 16;

  // 1. bf16 conversions (x, wq, wk, wv) in one dispatch
  k_cvt4<<<32768, 256, 0, stream>>>(x, wq_w, wk_w, wv_w, s0, s1, s2, s3);

  // 2. LoRA intermediates (fp32 exact, from fp32 x)
  k_lora_t<<<128, 256, 0, stream>>>(x, wq_a, wv_a, t_q, t_v);

  // 3. projections (256x256 8-phase bf16 MFMA; LoRA rank-16 fp32 epilogue for Q and V)
  k_gemm<true,  false><<<256, 512, 0, stream>>>(s0, s1, nullptr, s4, t_q, wq_b);        // Qb
  k_gemm<false, false><<<256, 512, 0, stream>>>(s0, s2, nullptr, s5, nullptr, nullptr); // Kb
  k_gemm<true,  false><<<256, 512, 0, stream>>>(s0, s3, nullptr, s6, t_v, wv_b);        // Vb

  // 4. RoPE Q (+1/sqrt(HD)) and K -> (b,h,s,d) bf16, one dispatch
  k_rope2<<<32768, 256, 0, stream>>>(s4, s5, s2, s3, fc, fs);  // Qb->q_bf(s2), Kb->k_bf(s3)

  // 5. V -> (b,h,d,s) bf16 (into s4; Qb dead)  +  wo convert (into s0; x_bf dead)
  k_vt_cvt<<<24576, 256, 0, stream>>>(s6, s4, wo_w, s0);

  // 6. causal flash attention v2 -> (b,s,h*d) bf16 (wq_bf slot s1 dead)
  k_attn<<<2048, 256, 0, stream>>>(s2, s3, s4, s1);

  // 7. output projection -> fp32 d_out
  k_gemm<false, true><<<256, 512, 0, stream>>>(s1, s0, (float*)d_out, nullptr, nullptr, nullptr);
}

// Round 9
// 1002.660 us; speedup vs baseline: 3.4663x; 1.1591x over previous
//
#include <hip/hip_runtime.h>

typedef unsigned short u16;
typedef unsigned int   u32;

typedef __bf16 bf16x8 __attribute__((ext_vector_type(8)));
typedef float  f32x4  __attribute__((ext_vector_type(4)));

typedef __attribute__((address_space(1))) const u32* gas_u32;
typedef __attribute__((address_space(3))) u32*       las_u32;

#define B_  4
#define S_  1024
#define D_  4096
#define H_  32
#define HD_ 128
#define M_  4096

__device__ __forceinline__ void gload16(const void* g, void* l) {
  __builtin_amdgcn_global_load_lds((gas_u32)g, (las_u32)l, 16, 0, 0);
}

__device__ __forceinline__ u16 f2b(float x) {
  u32 u = __float_as_uint(x);
  u32 r = (u + 0x7fffu + ((u >> 16) & 1u)) >> 16;
  return (u16)r;
}
__device__ __forceinline__ float b2f(u16 x) {
  return __uint_as_float((u32)x << 16);
}

// ------ fp32 -> bf16 convert: 4 tensors + t_q/t_v zero-init in one dispatch ---------
__global__ __launch_bounds__(256) void k_cvt4(const float* __restrict__ sa,
                                              const float* __restrict__ sb,
                                              const float* __restrict__ sc,
                                              const float* __restrict__ sd,
                                              u16* __restrict__ da,
                                              u16* __restrict__ db,
                                              u16* __restrict__ dc,
                                              u16* __restrict__ dd,
                                              float* __restrict__ tz) {
  const int bid = blockIdx.x;
  if (bid >= 32768) {                       // 32 blocks zero t_q+t_v (512 KB)
    size_t i = ((size_t)(bid - 32768) * 256 + threadIdx.x) * 4;
    float4 z = (float4){0.f, 0.f, 0.f, 0.f};
    #pragma unroll
    for (int k = 0; k < 4; k++) ((float4*)tz)[i + k] = z;
    return;
  }
  const int sel = bid >> 13;                // 4 x 8192 blocks
  const float* src = sel == 0 ? sa : sel == 1 ? sb : sel == 2 ? sc : sd;
  u16*         dst = sel == 0 ? da : sel == 1 ? db : sel == 2 ? dc : dd;
  size_t i = (size_t)(bid & 8191) * 256 + threadIdx.x;
  const float4* s = (const float4*)src + i * 2;
  float4 a = s[0], b = s[1];
  uint4 o;
  o.x = (u32)f2b(a.x) | ((u32)f2b(a.y) << 16);
  o.y = (u32)f2b(a.z) | ((u32)f2b(a.w) << 16);
  o.z = (u32)f2b(b.x) | ((u32)f2b(b.y) << 16);
  o.w = (u32)f2b(b.z) | ((u32)f2b(b.w) << 16);
  ((uint4*)dst)[i] = o;
}

// ---- LoRA intermediates, split-K x8: t_q += x@wq_a^T, t_v += x@wv_a^T (fp32) --------
// 1024 blocks: rowgroup = bid>>3 (32 m-rows), ksplit = bid&7 (512 K). atomicAdd merge.
__global__ __launch_bounds__(256) void k_lora_t(const float* __restrict__ x,
                                                const float* __restrict__ wqa,
                                                const float* __restrict__ wva,
                                                float* __restrict__ tq,
                                                float* __restrict__ tv) {
  __shared__ float xs[32][136];
  __shared__ float was[32][136];
  const int tid = threadIdx.x;
  const int m0 = (blockIdx.x >> 3) * 32;
  const int k0 = (blockIdx.x & 7) * 512;
  const int mr = tid >> 3, rg = tid & 7;
  float a0 = 0.f, a1 = 0.f, a2 = 0.f, a3 = 0.f;
  for (int kc = k0; kc < k0 + 512; kc += 128) {
    #pragma unroll
    for (int i = 0; i < 4; i++) {
      int e = (tid + 256 * i) * 4;
      int row = e >> 7, col = e & 127;
      *(float4*)&xs[row][col] = *(const float4*)&x[(size_t)(m0 + row) * 4096 + kc + col];
      const float* wsrc = (row < 16) ? &wqa[row * 4096 + kc + col]
                                     : &wva[(row - 16) * 4096 + kc + col];
      *(float4*)&was[row][col] = *(const float4*)wsrc;
    }
    __syncthreads();
    #pragma unroll 8
    for (int ks = 0; ks < 32; ks++) {
      float4 xv = *(float4*)&xs[mr][ks * 4];
      float4 w0 = *(float4*)&was[rg][ks * 4];
      float4 w1 = *(float4*)&was[rg + 8][ks * 4];
      float4 w2 = *(float4*)&was[rg + 16][ks * 4];
      float4 w3 = *(float4*)&was[rg + 24][ks * 4];
      a0 += xv.x * w0.x + xv.y * w0.y + xv.z * w0.z + xv.w * w0.w;
      a1 += xv.x * w1.x + xv.y * w1.y + xv.z * w1.z + xv.w * w1.w;
      a2 += xv.x * w2.x + xv.y * w2.y + xv.z * w2.z + xv.w * w2.w;
      a3 += xv.x * w3.x + xv.y * w3.y + xv.z * w3.z + xv.w * w3.w;
    }
    __syncthreads();
  }
  atomicAdd(&tq[(m0 + mr) * 16 + rg],     a0);
  atomicAdd(&tq[(m0 + mr) * 16 + rg + 8], a1);
  atomicAdd(&tv[(m0 + mr) * 16 + rg],     a2);
  atomicAdd(&tv[(m0 + mr) * 16 + rg + 8], a3);
}

// ===================== 256x256 8-phase GEMM (T2+T3+T4+T5 template) ===================
#define BAR() do { __builtin_amdgcn_sched_barrier(0); __builtin_amdgcn_s_barrier(); \
                   __builtin_amdgcn_sched_barrier(0); } while (0)
#define VMCNT4() asm volatile("s_waitcnt vmcnt(4)" ::: "memory")
#define VMCNT8() asm volatile("s_waitcnt vmcnt(8)" ::: "memory")
#define VMCNT0() asm volatile("s_waitcnt vmcnt(0)" ::: "memory")

#define STAGE(buf, tens, s, t) \
  gload16(((tens) ? Bw : A) + ((tens) ? offB[s] : offA[s]) + (t) * 64, \
          &lds.g[(buf) * 32768 + (tens) * 16384 + (s) * 4096 + tid * 8])

#define LDA(buf, h) do { \
  _Pragma("unroll") for (int i_ = 0; i_ < 4; i_++) { \
    const int r_ = ((h) * 128 + wm * 64 + i_ * 16 + fr) * 64; \
    a[i_][0] = *(const bf16x8*)&lds.g[(buf) * 32768 + r_ + ck0]; \
    a[i_][1] = *(const bf16x8*)&lds.g[(buf) * 32768 + r_ + ck0 + 32]; } } while (0)

#define LDB(buf, x, bb) do { \
  _Pragma("unroll") for (int j_ = 0; j_ < 2; j_++) { \
    const int r_ = ((x) * 128 + wn * 32 + j_ * 16 + fr) * 64; \
    bb[j_][0] = *(const bf16x8*)&lds.g[(buf) * 32768 + 16384 + r_ + ck0]; \
    bb[j_][1] = *(const bf16x8*)&lds.g[(buf) * 32768 + 16384 + r_ + ck0 + 32]; } } while (0)

#define DO_MFMA(h, x, bb) do { \
  __builtin_amdgcn_s_setprio(1); \
  _Pragma("unroll") for (int i_ = 0; i_ < 4; i_++) \
    _Pragma("unroll") for (int j_ = 0; j_ < 2; j_++) { \
      acc[(h) * 4 + i_][(x) * 2 + j_] = __builtin_amdgcn_mfma_f32_16x16x32_bf16( \
          a[i_][0], bb[j_][0], acc[(h) * 4 + i_][(x) * 2 + j_], 0, 0, 0); \
      acc[(h) * 4 + i_][(x) * 2 + j_] = __builtin_amdgcn_mfma_f32_16x16x32_bf16( \
          a[i_][1], bb[j_][1], acc[(h) * 4 + i_][(x) * 2 + j_], 0, 0, 0); } \
  __builtin_amdgcn_s_setprio(0); } while (0)

template<bool LORA, bool F32OUT>
__global__ __launch_bounds__(512, 2) void k_gemm(const u16* __restrict__ A,
                                                 const u16* __restrict__ Bw,
                                                 float* __restrict__ Cf,
                                                 u16* __restrict__ Cb,
                                                 const float* __restrict__ T,
                                                 const float* __restrict__ WB) {
  constexpr int K = 4096, N = 4096;
  __shared__ __align__(16) union {
    u16 g[2 * 2 * 16384];                       // 128 KB: [buf][A/B][16384 u16]
    struct { float t[256][20]; float w[256][20]; } ep;   // LoRA epilogue (40 KB)
  } lds;
  const int tid = threadIdx.x;
  const int lane = tid & 63, wid = tid >> 6;
  const int fr = lane & 15, fq = lane >> 4;
  const int wm = wid >> 2, wn = wid & 3;
  const int swz = (blockIdx.x & 7) * 32 + (blockIdx.x >> 3);   // XCD swizzle (256%8==0)
  const int m0 = (swz >> 4) << 8;
  const int n0 = (swz & 15) << 8;

  const int u = tid >> 3;
  const int cg = (tid & 7) ^ (((tid >> 5) & 1) << 1);          // st_16x32 swizzle
  u32 offA[4], offB[4];
  offA[0] = (u32)(m0 + u) * K + cg * 8;
  offA[1] = (u32)(m0 + u + 128) * K + cg * 8;
  offA[2] = (u32)(m0 + u + 64) * K + cg * 8;
  offA[3] = (u32)(m0 + u + 192) * K + cg * 8;
  const int ub = (u & 31), uh = (u >> 5);
  offB[0] = (u32)(n0 + ub + uh * 64) * K + cg * 8;
  offB[1] = (u32)(n0 + ub + 128 + uh * 64) * K + cg * 8;
  offB[2] = (u32)(n0 + ub + uh * 64 + 32) * K + cg * 8;
  offB[3] = (u32)(n0 + ub + 128 + uh * 64 + 32) * K + cg * 8;

  const int ck0 = (fq ^ (((fr >> 2) & 1) << 1)) * 8;

  f32x4 acc[8][4];
  #pragma unroll
  for (int i = 0; i < 8; i++)
    #pragma unroll
    for (int j = 0; j < 4; j++) acc[i][j] = (f32x4){0.f, 0.f, 0.f, 0.f};
  bf16x8 a[4][2], b0[2][2], b1[2][2];

  STAGE(0, 0, 0, 0); STAGE(0, 0, 1, 0); STAGE(0, 1, 0, 0); STAGE(0, 1, 1, 0);
  STAGE(0, 0, 2, 0); STAGE(0, 0, 3, 0); STAGE(0, 1, 2, 0); STAGE(0, 1, 3, 0);
  STAGE(1, 0, 0, 1); STAGE(1, 0, 1, 1); STAGE(1, 1, 0, 1); STAGE(1, 1, 1, 1);
  VMCNT4();
  BAR();

  for (int it = 0; it < 32; ++it) {
    const int t1 = (2 * it + 1) & 63, t2 = (2 * it + 2) & 63, t3 = (2 * it + 3) & 63;
    LDA(0, 0); LDB(0, 0, b0);
    STAGE(1, 0, 2, t1); STAGE(1, 0, 3, t1);
    BAR(); DO_MFMA(0, 0, b0); BAR();
    LDB(0, 1, b1);
    STAGE(1, 1, 2, t1); STAGE(1, 1, 3, t1);
    BAR(); DO_MFMA(0, 1, b1); BAR();
    LDA(0, 1);
    STAGE(0, 0, 0, t2); STAGE(0, 0, 1, t2);
    BAR(); DO_MFMA(1, 0, b0); BAR();
    STAGE(0, 1, 0, t2); STAGE(0, 1, 1, t2);
    VMCNT4();
    BAR(); DO_MFMA(1, 1, b1); BAR();
    LDA(1, 0); LDB(1, 0, b0);
    STAGE(0, 0, 2, t2); STAGE(0, 0, 3, t2);
    BAR(); DO_MFMA(0, 0, b0); BAR();
    LDB(1, 1, b1);
    STAGE(0, 1, 2, t2); STAGE(0, 1, 3, t2);
    BAR(); DO_MFMA(0, 1, b1); BAR();
    LDA(1, 1);
    STAGE(1, 0, 0, t3); STAGE(1, 0, 1, t3);
    BAR(); DO_MFMA(1, 0, b0); BAR();
    STAGE(1, 1, 0, t3); STAGE(1, 1, 1, t3);
    VMCNT4();
    BAR(); DO_MFMA(1, 1, b1); BAR();
  }

  __syncthreads();
  if (LORA) {
    const int row = tid >> 1, hf = (tid & 1) * 8;
    *(float4*)&lds.ep.t[row][hf]     = *(const float4*)&T[(m0 + row) * 16 + hf];
    *(float4*)&lds.ep.t[row][hf + 4] = *(const float4*)&T[(m0 + row) * 16 + hf + 4];
    *(float4*)&lds.ep.w[row][hf]     = *(const float4*)&WB[(n0 + row) * 16 + hf];
    *(float4*)&lds.ep.w[row][hf + 4] = *(const float4*)&WB[(n0 + row) * 16 + hf + 4];
    __syncthreads();
  }

  float wc[4][16];
  if (LORA) {
    #pragma unroll
    for (int q = 0; q < 4; q++) {
      const int coll = wn * 64 + (q >> 1) * 32 + (q & 1) * 16 + fr;
      #pragma unroll
      for (int r4 = 0; r4 < 4; r4++)
        *(float4*)&wc[q][r4 * 4] = *(float4*)&lds.ep.w[coll][r4 * 4];
    }
  }
  #pragma unroll
  for (int h = 0; h < 2; h++)
    #pragma unroll
    for (int i = 0; i < 4; i++)
      #pragma unroll
      for (int jj = 0; jj < 4; jj++) {
        const int rowl = wm * 128 + h * 64 + i * 16 + fq * 4 + jj;
        float tr[16];
        if (LORA) {
          #pragma unroll
          for (int r4 = 0; r4 < 4; r4++)
            *(float4*)&tr[r4 * 4] = *(float4*)&lds.ep.t[rowl][r4 * 4];
        }
        #pragma unroll
        for (int q = 0; q < 4; q++) {
          float v = acc[h * 4 + i][q][jj];
          if (LORA) {
            float d = 0.f;
            #pragma unroll
            for (int r = 0; r < 16; r++) d += tr[r] * wc[q][r];
            v += 2.0f * d;
          }
          const int col = n0 + wn * 64 + (q >> 1) * 32 + (q & 1) * 16 + fr;
          if (F32OUT) Cf[(size_t)(m0 + rowl) * N + col] = v;
          else        Cb[(size_t)(m0 + rowl) * N + col] = f2b(v);
        }
      }
}

// ---------------- RoPE both tensors: (b,s,h,d)bf16 -> (b,h,s,d)bf16 ------------------
__global__ __launch_bounds__(256) void k_rope2(const u16* __restrict__ qin,
                                               const u16* __restrict__ kin,
                                               u16* __restrict__ qout,
                                               u16* __restrict__ kout,
                                               const float* __restrict__ fc,
                                               const float* __restrict__ fs) {
  const int sel = blockIdx.x >> 14;
  const u16* in  = sel ? kin  : qin;
  u16*       out = sel ? kout : qout;
  const float scale = sel ? 1.0f : 0.08838834764831845f;
  const int tid = (blockIdx.x & 16383) * 256 + threadIdx.x;   // B*H*S*32 threads
  const int c4 = tid & 31;
  const int s  = (tid >> 5) & 1023;
  const int h  = (tid >> 15) & 31;
  const int b  = tid >> 20;
  const ushort4 v = *(const ushort4*)&in[(((size_t)(b * 1024 + s) * 32 + h) * 128) + c4 * 4];
  const float2 c = *(const float2*)&fc[s * 64 + c4 * 2];
  const float2 sn = *(const float2*)&fs[s * 64 + c4 * 2];
  float vx = b2f(v.x), vy = b2f(v.y), vz = b2f(v.z), vw = b2f(v.w);
  float o0 = (vx * c.x - vy * sn.x) * scale;
  float o1 = (vx * sn.x + vy * c.x) * scale;
  float o2 = (vz * c.y - vw * sn.y) * scale;
  float o3 = (vz * sn.y + vw * c.y) * scale;
  uint2 o;
  o.x = (u32)f2b(o0) | ((u32)f2b(o1) << 16);
  o.y = (u32)f2b(o2) | ((u32)f2b(o3) << 16);
  *(uint2*)&out[(((size_t)(b * 32 + h) * 1024 + s) * 128) + c4 * 4] = o;
}

// ---- fused: V transpose (b,s,h,d)->(b,h,d,s) [blocks 0..16383]  +  wo fp32->bf16 ----
__global__ __launch_bounds__(256) void k_vt_cvt(const u16* __restrict__ Vb,
                                                u16* __restrict__ vt,
                                                const float* __restrict__ wo,
                                                u16* __restrict__ wo_bf) {
  __shared__ u16 tile[32][36];
  const int bid = blockIdx.x;
  const int t = threadIdx.x;
  if (bid < 16384) {
    const int dt = bid & 3;
    const int st = (bid >> 2) & 31;
    const int bh = bid >> 7;
    const int r = t >> 3, c4 = (t & 7) * 4;
    const ushort4 v = *(const ushort4*)
        &Vb[((size_t)((bh >> 5) * 1024 + st * 32 + r) * 32 + (bh & 31)) * 128 + dt * 32 + c4];
    tile[r][c4] = v.x; tile[r][c4 + 1] = v.y; tile[r][c4 + 2] = v.z; tile[r][c4 + 3] = v.w;
    __syncthreads();
    uint2 o;
    o.x = (u32)tile[c4][r]     | ((u32)tile[c4 + 1][r] << 16);
    o.y = (u32)tile[c4 + 2][r] | ((u32)tile[c4 + 3][r] << 16);
    *(uint2*)&vt[((size_t)bh * 128 + dt * 32 + r) * 1024 + st * 32 + c4] = o;
  } else {
    size_t i = (size_t)(bid - 16384) * 256 + t;
    const float4* s = (const float4*)wo + i * 2;
    float4 a = s[0], b = s[1];
    uint4 o;
    o.x = (u32)f2b(a.x) | ((u32)f2b(a.y) << 16);
    o.y = (u32)f2b(a.z) | ((u32)f2b(a.w) << 16);
    o.z = (u32)f2b(b.x) | ((u32)f2b(b.y) << 16);
    o.w = (u32)f2b(b.z) | ((u32)f2b(b.w) << 16);
    ((uint4*)wo_bf)[i] = o;
  }
}

// ========= flash attention v3: 4 waves x 16 q-rows, KVBLK=64, LDS double-buffer =====
// bid -> xcd=bid&7, qblk=(bid>>3)&15, bh=(bid>>7)*8+xcd (K/V L2-resident per XCD).
// Per 64-k tile: K [64][128] + V^T [128][64], both XOR-swizzled (chunk ^= row&7),
// staged via global_load_lds (linear dest + pre-swizzled source), vmcnt(8) counted.
// At KVBLK=64 all 4 waves need exactly qblk+1 tiles (no idle-wave divergence).
__global__ __launch_bounds__(256) void k_attn(const u16* __restrict__ qb_,
                                              const u16* __restrict__ kb,
                                              const u16* __restrict__ vt,
                                              u16* __restrict__ ob) {
  __shared__ __align__(16) u16 KT[2][8192];     // [64 k][128 d]
  __shared__ __align__(16) u16 VT[2][8192];     // [128 d][64 k]
  __shared__ __align__(16) u16 PT[4][16 * 72];  // per-wave P, pad 72
  const int bid = blockIdx.x;
  const int xcd = bid & 7, qblk = (bid >> 3) & 15;
  const int bh = (bid >> 7) * 8 + xcd;
  const int q0b = qblk * 64;
  const int tid = threadIdx.x;
  const int w = tid >> 6, l = tid & 63;
  const int c = l & 15, g = l >> 4;
  const int q0 = q0b + w * 16;
  const u16* qbase = qb_ + (size_t)bh * (S_ * HD_);
  const u16* kbase = kb + (size_t)bh * (S_ * HD_);
  const u16* vbase = vt + (size_t)bh * (HD_ * S_);

  bf16x8 qf[4];
  #pragma unroll
  for (int ks = 0; ks < 4; ks++)
    qf[ks] = *(const bf16x8*)&qbase[(q0 + c) * 128 + ks * 32 + g * 8];
  f32x4 accO[8];
  #pragma unroll
  for (int d = 0; d < 8; d++) accO[d] = (f32x4){0.f, 0.f, 0.f, 0.f};
  float mrun[4] = {-1e30f, -1e30f, -1e30f, -1e30f};
  float lrun[4] = {0.f, 0.f, 0.f, 0.f};

  const int skc = ((tid & 15) ^ ((tid >> 4) & 7)) * 8;   // K stage swizzled chunk
  const int svc = ((tid & 7) ^ ((tid >> 3) & 7)) * 8;    // V stage swizzled chunk

#define STG_KV(buf, kt) do { \
    _Pragma("unroll") for (int p_ = 0; p_ < 4; p_++) \
      gload16(kbase + (size_t)((kt) * 64 + p_ * 16 + (tid >> 4)) * 128 + skc, \
              &KT[buf][p_ * 2048 + tid * 8]); \
    _Pragma("unroll") for (int p_ = 0; p_ < 4; p_++) \
      gload16(vbase + (size_t)(p_ * 32 + (tid >> 3)) * 1024 + (kt) * 64 + svc, \
              &VT[buf][p_ * 2048 + tid * 8]); \
  } while (0)

  STG_KV(0, 0);
  for (int kbi = 0; kbi <= qblk; kbi++) {
    const int cur = kbi & 1;
    if (kbi < qblk) {
      STG_KV(cur ^ 1, kbi + 1);
      VMCNT8();
    } else {
      VMCNT0();
    }
    BAR();
    f32x4 st[4];
    #pragma unroll
    for (int t = 0; t < 4; t++) st[t] = (f32x4){0.f, 0.f, 0.f, 0.f};
    #pragma unroll
    for (int ks = 0; ks < 4; ks++) {
      const int ch = ((ks * 4 + g) ^ (c & 7)) * 8;
      #pragma unroll
      for (int t = 0; t < 4; t++) {
        bf16x8 kf = *(const bf16x8*)&KT[cur][(t * 16 + c) * 128 + ch];
        st[t] = __builtin_amdgcn_mfma_f32_16x16x32_bf16(qf[ks], kf, st[t], 0, 0, 0);
      }
    }
    if (kbi == qblk) {             // only final tile is causally partial (all waves)
      #pragma unroll
      for (int t = 0; t < 4; t++)
        #pragma unroll
        for (int j = 0; j < 4; j++)
          if (t * 16 + c > w * 16 + g * 4 + j) st[t][j] = -1e9f;
    }
    float corr[4];
    #pragma unroll
    for (int j = 0; j < 4; j++) {
      float mx = fmaxf(fmaxf(st[0][j], st[1][j]), fmaxf(st[2][j], st[3][j]));
      #pragma unroll
      for (int off = 8; off; off >>= 1) mx = fmaxf(mx, __shfl_xor(mx, off, 16));
      float mn = fmaxf(mrun[j], mx);
      corr[j] = __expf(mrun[j] - mn);
      mrun[j] = mn;
      float p0 = __expf(st[0][j] - mn);
      float p1 = __expf(st[1][j] - mn);
      float p2 = __expf(st[2][j] - mn);
      float p3 = __expf(st[3][j] - mn);
      float rs = (p0 + p1) + (p2 + p3);
      #pragma unroll
      for (int off = 8; off; off >>= 1) rs += __shfl_xor(rs, off, 16);
      lrun[j] = lrun[j] * corr[j] + rs;
      const int pr = (g * 4 + j) * 72;
      PT[w][pr + c]      = f2b(p0);
      PT[w][pr + 16 + c] = f2b(p1);
      PT[w][pr + 32 + c] = f2b(p2);
      PT[w][pr + 48 + c] = f2b(p3);
    }
    asm volatile("s_waitcnt lgkmcnt(0)" ::: "memory");
    __builtin_amdgcn_sched_barrier(0);
    bf16x8 pa0 = *(const bf16x8*)&PT[w][c * 72 + g * 8];
    bf16x8 pa1 = *(const bf16x8*)&PT[w][c * 72 + 32 + g * 8];
    #pragma unroll
    for (int d = 0; d < 8; d++) {
      #pragma unroll
      for (int j = 0; j < 4; j++) accO[d][j] *= corr[j];
    }
    #pragma unroll
    for (int d = 0; d < 8; d++) {
      const int vr = (d * 16 + c) * 64;
      bf16x8 vf0 = *(const bf16x8*)&VT[cur][vr + ((g ^ (c & 7)) * 8)];
      bf16x8 vf1 = *(const bf16x8*)&VT[cur][vr + (((4 + g) ^ (c & 7)) * 8)];
      accO[d] = __builtin_amdgcn_mfma_f32_16x16x32_bf16(pa0, vf0, accO[d], 0, 0, 0);
      accO[d] = __builtin_amdgcn_mfma_f32_16x16x32_bf16(pa1, vf1, accO[d], 0, 0, 0);
    }
    BAR();
  }
#undef STG_KV

  float inv[4];
  #pragma unroll
  for (int j = 0; j < 4; j++) inv[j] = 1.0f / lrun[j];
  #pragma unroll
  for (int d = 0; d < 8; d++) {
    #pragma unroll
    for (int j = 0; j < 4; j++) {
      float val = accO[d][j] * inv[j];
      ob[(size_t)((bh >> 5) * 1024 + q0 + g * 4 + j) * 4096 + (bh & 31) * 128 + d * 16 + c]
          = f2b(val);
    }
  }
}

// =====================================================================================
extern "C" void kernel_launch(void* const* d_in, const int* in_sizes, int n_in,
                              void* d_out, int out_size, void* d_ws, size_t ws_size,
                              hipStream_t stream) {
  const float* x    = (const float*)d_in[0];
  const float* wq_w = (const float*)d_in[1];
  const float* wq_a = (const float*)d_in[2];
  const float* wq_b = (const float*)d_in[3];
  const float* wk_w = (const float*)d_in[4];
  const float* wv_w = (const float*)d_in[5];
  const float* wv_a = (const float*)d_in[6];
  const float* wv_b = (const float*)d_in[7];
  const float* wo_w = (const float*)d_in[8];
  const float* fc   = (const float*)d_in[9];
  const float* fs   = (const float*)d_in[10];
  // d_in[11] = mask (causal, applied analytically), d_in[12] = start_pos (0)

  char* p = (char*)d_ws;
  const size_t SZ_BF = (size_t)M_ * D_ * 2;   // 32 MB
  u16* s0 = (u16*)(p + 0 * SZ_BF);   // x_bf   -> wo_bf
  u16* s1 = (u16*)(p + 1 * SZ_BF);   // wq_bf  -> att_bf
  u16* s2 = (u16*)(p + 2 * SZ_BF);   // wk_bf  -> q_bf
  u16* s3 = (u16*)(p + 3 * SZ_BF);   // wv_bf  -> k_bf
  u16* s4 = (u16*)(p + 4 * SZ_BF);   // Qb     -> v_t
  u16* s5 = (u16*)(p + 5 * SZ_BF);   // Kb
  u16* s6 = (u16*)(p + 6 * SZ_BF);   // Vb
  float* t_q = (float*)(p + 7 * SZ_BF);
  float* t_v = t_q + (size_t)M_ * 16;

  // 1. bf16 conversions (x, wq, wk, wv) + zero t_q/t_v, one dispatch
  k_cvt4<<<32800, 256, 0, stream>>>(x, wq_w, wk_w, wv_w, s0, s1, s2, s3, t_q);

  // 2. LoRA intermediates (fp32, split-K x8, atomic merge)
  k_lora_t<<<1024, 256, 0, stream>>>(x, wq_a, wv_a, t_q, t_v);

  // 3. projections (256x256 8-phase bf16 MFMA; LoRA rank-16 fp32 epilogue for Q and V)
  k_gemm<true,  false><<<256, 512, 0, stream>>>(s0, s1, nullptr, s4, t_q, wq_b);        // Qb
  k_gemm<false, false><<<256, 512, 0, stream>>>(s0, s2, nullptr, s5, nullptr, nullptr); // Kb
  k_gemm<true,  false><<<256, 512, 0, stream>>>(s0, s3, nullptr, s6, t_v, wv_b);        // Vb

  // 4. RoPE Q (+1/sqrt(HD)) and K -> (b,h,s,d) bf16, one dispatch
  k_rope2<<<32768, 256, 0, stream>>>(s4, s5, s2, s3, fc, fs);  // Qb->q_bf(s2), Kb->k_bf(s3)

  // 5. V -> (b,h,d,s) bf16 (into s4; Qb dead)  +  wo convert (into s0; x_bf dead)
  k_vt_cvt<<<24576, 256, 0, stream>>>(s6, s4, wo_w, s0);

  // 6. causal flash attention v3 (KVBLK=64) -> (b,s,h*d) bf16 (wq_bf slot s1 dead)
  k_attn<<<2048, 256, 0, stream>>>(s2, s3, s4, s1);

  // 7. output projection -> fp32 d_out
  k_gemm<false, true><<<256, 512, 0, stream>>>(s1, s0, (float*)d_out, nullptr, nullptr, nullptr);
}